// Round 10
// baseline (216.400 us; speedup 1.0000x reference)
//
#include <hip/hip_runtime.h>
#include <cstdint>
#include <cstddef>

// Problem constants
#define BB 2
#define SS 2048
#define DD 1024
#define HH 16
#define HDIM 64
// Attention scale 1/sqrt(64)=0.125 and the exp->exp2 fold log2(e) are
// pre-multiplied into q at the gemm_qkv epilogue: 0.125*1.4426950 = 0.18033688.

typedef short bf16x8 __attribute__((ext_vector_type(8)));
typedef short bf16x4 __attribute__((ext_vector_type(4)));
typedef float f32x4 __attribute__((ext_vector_type(4)));

union U4S8 { uint4 u; bf16x8 s; };
union U2S4 { uint2 u; bf16x4 s; unsigned short h[4]; };

// 16x16x16 bf16 MFMA (K=16). __has_builtin(amdgcn) is FALSE in the host pass
// of HIP's dual compile — guard with __HIP_DEVICE_COMPILE__, dummy for host.
#if defined(__HIP_DEVICE_COMPILE__)
# if __has_builtin(__builtin_amdgcn_mfma_f32_16x16x16bf16_1k)
#  define MFMA_PV(a, b, c) __builtin_amdgcn_mfma_f32_16x16x16bf16_1k((a), (b), (c), 0, 0, 0)
# else
#  define MFMA_PV(a, b, c) __builtin_amdgcn_mfma_f32_16x16x16_bf16((a), (b), (c), 0, 0, 0)
# endif
#else
# define MFMA_PV(a, b, c) (c)
#endif

__device__ __forceinline__ unsigned short f2bf(float f) {
    union { float f; unsigned int u; } c; c.f = f;
    unsigned int u = c.u;
    unsigned int r = (u + 0x7FFFu + ((u >> 16) & 1u)) >> 16;  // RTNE
    return (unsigned short)r;
}

// async global->LDS, 16B per lane. LDS dest must be wave-uniform base + lane*16.
__device__ __forceinline__ void async_cp16(const void* g, void* l) {
    __builtin_amdgcn_global_load_lds(
        (const __attribute__((address_space(1))) void*)g,
        (__attribute__((address_space(3))) void*)l, 16, 0, 0);
}

// ---------------------------------------------------------------- fp32 -> bf16
// One kernel for all three inputs (x:524288, w_qkv:393216, w_out:131072 uint4s).
__global__ __launch_bounds__(256) void cvt_all(
    const float* __restrict__ x, const float* __restrict__ wq,
    const float* __restrict__ wo,
    unsigned short* __restrict__ xb, unsigned short* __restrict__ wqb,
    unsigned short* __restrict__ wob) {
    int i = blockIdx.x * 256 + threadIdx.x;
    const float* in; unsigned short* out; int j;
    if (i < 524288)       { in = x;  out = xb;  j = i; }
    else if (i < 917504)  { in = wq; out = wqb; j = i - 524288; }
    else                  { in = wo; out = wob; j = i - 917504; }
    float4 a = ((const float4*)in)[2 * j];
    float4 b = ((const float4*)in)[2 * j + 1];
    union { uint4 u; unsigned short h[8]; } o;
    o.h[0] = f2bf(a.x); o.h[1] = f2bf(a.y); o.h[2] = f2bf(a.z); o.h[3] = f2bf(a.w);
    o.h[4] = f2bf(b.x); o.h[5] = f2bf(b.y); o.h[6] = f2bf(b.z); o.h[7] = f2bf(b.w);
    ((uint4*)out)[j] = o.u;
}

// ---------------------------------------------------------------- QKV GEMM
// C[m,e] = sum_d x[m,d] * w_qkv[e,d]  (NT). M=4096, N=3072, K=1024.
// 128x128 tile, BK=32, async global_load_lds DOUBLE-buffered staging (one
// barrier per BK). The epilogue transpose buffer Tr ALIASES the staging LDS
// (disjoint in time, __syncthreads before reuse) -> total LDS 36 KB ->
// 4 blocks/CU (was 3 at 52 KB).
__global__ __launch_bounds__(256) void gemm_qkv(
    const unsigned short* __restrict__ A,   // x_bf   [4096][1024]
    const unsigned short* __restrict__ Bw,  // wqkv_bf[3072][1024]
    unsigned short* __restrict__ qb, unsigned short* __restrict__ kb,
    unsigned short* __restrict__ vb) {
    const int K = 1024;
    // layout: buf0 { As 4096 | Bs 4096 } buf1 { As | Bs } = 16384 shorts (32 KB)
    // Tr alias: 4 waves x 64x72 = 18432 shorts (36 KB)
    __shared__ unsigned short smem[18432];
    int tid = threadIdx.x;
    int lane = tid & 63, wave = tid >> 6;
    int wm = (wave & 1) * 64, wn = (wave >> 1) * 64;
    int m0 = blockIdx.y * 128, n0 = blockIdx.x * 128;
    int lm = lane & 15, lq = lane >> 4;

    f32x4 acc[4][4] = {};

    int sdst = tid * 8;  // shorts; lane-contiguous dest
    const unsigned short* gA = A  + (size_t)(m0 + (tid >> 2)) * K + (tid & 3) * 8;
    const unsigned short* gB = Bw + (size_t)(n0 + (tid >> 2)) * K + (tid & 3) * 8;

#define GSTAGE(k0, buf) do {                                          \
        async_cp16(gA + (k0),          smem + (buf) + sdst);          \
        async_cp16(gA + 64 * K + (k0), smem + (buf) + 2048 + sdst);   \
        async_cp16(gB + (k0),          smem + (buf) + 4096 + sdst);   \
        async_cp16(gB + 64 * K + (k0), smem + (buf) + 6144 + sdst);   \
    } while (0)

    GSTAGE(0, 0);
    for (int k0 = 0; k0 < K; k0 += 64) {
        #pragma unroll
        for (int hf = 0; hf < 2; hf++) {
            int base = hf ? 8192 : 0;
            int obuf = hf ? 0 : 8192;
            __syncthreads();  // drains this buffer's loads; other buffer free
            int kn = k0 + 32 + hf * 32;
            if (kn < K) GSTAGE(kn, obuf);
            const unsigned short* As = smem + base;
            const unsigned short* Bs = smem + base + 4096;
            U4S8 af[4], bfx[4];
            #pragma unroll
            for (int i = 0; i < 4; i++) {
                af[i].u  = *(const uint4*)(As + (wm + i * 16 + lm) * 32 + lq * 8);
                bfx[i].u = *(const uint4*)(Bs + (wn + i * 16 + lm) * 32 + lq * 8);
            }
            #pragma unroll
            for (int mi = 0; mi < 4; mi++)
                #pragma unroll
                for (int ni = 0; ni < 4; ni++)
                    acc[mi][ni] = __builtin_amdgcn_mfma_f32_16x16x32_bf16(
                        af[mi].s, bfx[ni].s, acc[mi][ni], 0, 0, 0);
        }
    }
#undef GSTAGE
    __syncthreads();  // all waves done with staging LDS before Tr alias reuse

    // Epilogue. C/D layout: col=lane&15, row=(lane>>4)*4+reg.
    if (n0 < 1024) {
        // ---- v: transpose wave's 64x64 subtile via LDS, store [B,H,HD,S] coalesced
        int h = (n0 + wn) >> 6;
        unsigned short* Trw = smem + wave * 4608;  // 64x72
        #pragma unroll
        for (int mi = 0; mi < 4; mi++)
            #pragma unroll
            for (int ni = 0; ni < 4; ni++)
                #pragma unroll
                for (int r = 0; r < 4; r++)
                    Trw[(ni * 16 + lm) * 72 + mi * 16 + lq * 4 + r] =
                        f2bf(acc[mi][ni][r]);
        __builtin_amdgcn_wave_barrier();
        int b = m0 >> 11;
        int s_base = (m0 + wm) & 2047;
        unsigned short* vdst = vb + ((size_t)(b * HH + h) * HDIM) * SS + s_base;
        #pragma unroll
        for (int it = 0; it < 8; it++) {
            int hd = it * 8 + (lane >> 3);
            int so = (lane & 7) * 8;
            uint4 val = *(const uint4*)&Trw[hd * 72 + so];
            *(uint4*)(vdst + (size_t)hd * SS + so) = val;
        }
    } else {
        bool isq = n0 < 2048;
        unsigned short* dst = isq ? qb : kb;
        float scale = isq ? 0.18033688f : 1.0f;  // q: fold softmax scale * log2(e)
        #pragma unroll
        for (int mi = 0; mi < 4; mi++) {
            int gr = m0 + wm + mi * 16 + lq * 4;
            #pragma unroll
            for (int ni = 0; ni < 4; ni++) {
                int gc = n0 + wn + ni * 16 + lm;
                int rem = gc & 1023;
                int h = rem >> 6, hd = rem & 63;
                #pragma unroll
                for (int r = 0; r < 4; r++) {
                    int row = gr + r;
                    int b = row >> 11, s = row & 2047;
                    dst[(((size_t)b * HH + h) * SS + s) * HDIM + hd] =
                        f2bf(acc[mi][ni][r] * scale);
                }
            }
        }
    }
}

// ---------------------------------------------------------------- Flash attention
// Transposed register-P scheme (S^T = K·Q^T, O^T += V^T·P^T), async dbuf LDS,
// XOR-swizzled conflict-free reads. VALU diet (round 10):
//  * P pairs packed with v_perm_b32 (3 ops/pair)
//  * softmax denominator via ones-vector MFMA on the SAME bf16 P used for PV
//    (kills 16 VALU adds/tile + the final shuffle reduce; exact numerator/
//    denominator consistency)
// Q-tile 64 (grid 1024 = 4 blocks/CU), K-tile 64, 4 waves x 16 Q-rows.
__global__ __launch_bounds__(256) void attn(
    const unsigned short* __restrict__ qb,  // [B,H,S,HD] pre-scaled (incl. log2e)
    const unsigned short* __restrict__ kb,  // [B,H,S,HD]
    const unsigned short* __restrict__ vb,  // [B,H,HD,S] (transposed)
    unsigned short* __restrict__ ob) {      // [B,S,D]
    int bh = blockIdx.y;
    int q0 = blockIdx.x * 64;
    int tid = threadIdx.x, lane = tid & 63, wave = tid >> 6;
    int lm = lane & 15, lq = lane >> 4;

    // Double buffer: [bufA: Kt 64x64 | Vt 64x64][bufB: same] = 32 KB, no padding.
    __shared__ unsigned short smem[4 * 4096];

    const unsigned short* qg = qb + (size_t)bh * SS * HDIM;
    const unsigned short* kg = kb + (size_t)bh * SS * HDIM;
    const unsigned short* vg = vb + (size_t)bh * HDIM * SS;

    // Q fragments, B-operand of S^T: n=q=lane&15, k=hd=lq*8+j
    U4S8 qf[2];
    #pragma unroll
    for (int ks = 0; ks < 2; ks++)
        qf[ks].u = *(const uint4*)(
            qg + (size_t)(q0 + wave * 16 + lm) * HDIM + ks * 32 + lq * 8);

    f32x4 oacc[4] = {};   // O^T[hd-tile]: col=q=lm, row=hd=lq*4+r (+16*mi2)
    f32x4 sacc = {};      // denominator: ones-MFMA row sums (all rows identical)

    U2S4 aones;           // bf16 1.0 broadcast (A-operand of the sum MFMA)
    aones.u.x = 0x3F803F80u; aones.u.y = 0x3F803F80u;

    // ---- loop-invariant swizzled LDS read indices (shorts)
    int lm7 = lm & 7;
    int kidx = lm * 64 + 8 * (lq ^ lm7);          // kf chunk lq (hd 0..31)
    int vidx[4];
    #pragma unroll
    for (int kc = 0; kc < 4; kc++)
        vidx[kc] = lm * 64 + 8 * (((kc << 1) | (lq >> 1)) ^ lm7) + (lq & 1) * 4;

    // ---- staging indices (async: dest = wave-uniform base + lane*16B)
    int srow = tid >> 3;                  // 0..31
    int scl  = (tid & 7) ^ (srow & 7);    // logical chunk for physical chunk tid&7
    int sdst = tid * 8;                   // shorts
    const unsigned short* ksrc0 = kg + (size_t)srow * HDIM + scl * 8;
    const unsigned short* vsrc0 = vg + (size_t)srow * SS + scl * 8;

    #define STAGE(ktile, buf)                                                   \
        do {                                                                    \
            int _o = (ktile) * 64;                                              \
            async_cp16(ksrc0 + (size_t)_o * HDIM,        smem + (buf) + sdst);         \
            async_cp16(ksrc0 + (size_t)(_o + 32) * HDIM, smem + (buf) + 2048 + sdst);  \
            async_cp16(vsrc0 + _o,                       smem + (buf) + 4096 + sdst);  \
            async_cp16(vsrc0 + (size_t)32 * SS + _o,     smem + (buf) + 6144 + sdst);  \
        } while (0)

    STAGE(0, 0);

    for (int kt = 0; kt < SS / 64; kt += 2) {
        #pragma unroll
        for (int hf = 0; hf < 2; hf++) {
            int base = hf ? 8192 : 0;       // compute buffer
            int obuf = hf ? 0 : 8192;       // stage target (other buffer)
            __syncthreads();  // drains vmcnt: this buffer's loads landed
            STAGE((kt + 1 + hf) & 31, obuf);  // wraps harmlessly on last iter

            // ---- S^T then P^T = 2^(S^T): pack pairs via v_perm; sum via MFMA
            U2S4 pb[4];
            #pragma unroll
            for (int mi = 0; mi < 4; mi++) {
                U4S8 kf0, kf1;
                kf0.u = *(const uint4*)(smem + base + mi * 1024 + kidx);
                kf1.u = *(const uint4*)(smem + base + mi * 1024 + (kidx ^ 32));
                f32x4 sa = {};
                sa = __builtin_amdgcn_mfma_f32_16x16x32_bf16(kf0.s, qf[0].s, sa, 0, 0, 0);
                sa = __builtin_amdgcn_mfma_f32_16x16x32_bf16(kf1.s, qf[1].s, sa, 0, 0, 0);
                unsigned int b0 = __float_as_uint(exp2f(sa[0])) + 0x8000u;
                unsigned int b1 = __float_as_uint(exp2f(sa[1])) + 0x8000u;
                unsigned int b2 = __float_as_uint(exp2f(sa[2])) + 0x8000u;
                unsigned int b3 = __float_as_uint(exp2f(sa[3])) + 0x8000u;
                pb[mi].u.x = __builtin_amdgcn_perm(b1, b0, 0x07060302u);
                pb[mi].u.y = __builtin_amdgcn_perm(b3, b2, 0x07060302u);
                sacc = MFMA_PV(aones.s, pb[mi].s, sacc);  // denom on MFMA pipe
            }

            // ---- O^T[hd][q] += V^T[hd][k] * P^T[k][q]  (16x16x16)
            #pragma unroll
            for (int mi2 = 0; mi2 < 4; mi2++) {
                #pragma unroll
                for (int kc = 0; kc < 4; kc++) {
                    U2S4 vf;
                    vf.u = *(const uint2*)(smem + base + 4096 + mi2 * 1024 + vidx[kc]);
                    oacc[mi2] = MFMA_PV(vf.s, pb[kc].s, oacc[mi2]);
                }
            }
        }
    }
    #undef STAGE

    // every lane's sacc[0] = full sum over k for its q=lm (all C rows identical)
    float inv = 1.f / sacc[0];

    // ---- transpose O^T back via smem, store coalesced bf16 [B,S,D]
    __syncthreads();  // all compute done; drains the wrapped stray loads
    unsigned short* Ow = smem + wave * (16 * 72);
    #pragma unroll
    for (int mi2 = 0; mi2 < 4; mi2++) {
        U2S4 t;
        #pragma unroll
        for (int r = 0; r < 4; r++)
            t.h[r] = f2bf(oacc[mi2][r] * inv);
        *(uint2*)&Ow[lm * 72 + mi2 * 16 + lq * 4] = t.u;
    }
    __builtin_amdgcn_wave_barrier();  // Ow wave-local
    int b = bh >> 4, h = bh & 15;
    #pragma unroll
    for (int it = 0; it < 2; it++) {
        int q  = it * 8 + (lane >> 3);
        int off = (lane & 7) * 8;
        uint4 val = *(const uint4*)&Ow[q * 72 + off];
        int srw = q0 + wave * 16 + q;
        *(uint4*)(ob + (size_t)(b * SS + srw) * DD + h * 64 + off) = val;
    }
}

// ---------------------------------------------------------------- Output GEMM
// out[m,e] = sum_d o[m,d] * w_out[e,d] + b_out[e].  M=4096, N=1024, K=1024.
// 128x64 tile -> 512 blocks (2/CU); async dbuf staging, one barrier per BK.
__global__ __launch_bounds__(256) void gemm_out(
    const unsigned short* __restrict__ A,   // o_bf   [4096][1024]
    const unsigned short* __restrict__ Bw,  // wout_bf[1024][1024]
    const float* __restrict__ bias, float* __restrict__ out) {
    const int K = 1024;
    // buf { As 4096 | Bs 2048 } x2 = 12288 shorts (24 KB)
    __shared__ unsigned short smem[12288];
    int tid = threadIdx.x;
    int lane = tid & 63, wave = tid >> 6;
    int wm = (wave & 1) * 64, wn = (wave >> 1) * 32;
    int m0 = blockIdx.y * 128, n0 = blockIdx.x * 64;
    int lm = lane & 15, lq = lane >> 4;

    f32x4 acc[4][2] = {};

    int sdst = tid * 8;
    const unsigned short* gA = A  + (size_t)(m0 + (tid >> 2)) * K + (tid & 3) * 8;
    const unsigned short* gB = Bw + (size_t)(n0 + (tid >> 2)) * K + (tid & 3) * 8;

#define OSTAGE(k0, buf) do {                                          \
        async_cp16(gA + (k0),          smem + (buf) + sdst);          \
        async_cp16(gA + 64 * K + (k0), smem + (buf) + 2048 + sdst);   \
        async_cp16(gB + (k0),          smem + (buf) + 4096 + sdst);   \
    } while (0)

    OSTAGE(0, 0);
    for (int k0 = 0; k0 < K; k0 += 64) {
        #pragma unroll
        for (int hf = 0; hf < 2; hf++) {
            int base = hf ? 6144 : 0;
            int obuf = hf ? 0 : 6144;
            __syncthreads();
            int kn = k0 + 32 + hf * 32;
            if (kn < K) OSTAGE(kn, obuf);
            const unsigned short* As = smem + base;
            const unsigned short* Bs = smem + base + 4096;
            U4S8 af[4], bfx[2];
            #pragma unroll
            for (int i = 0; i < 4; i++)
                af[i].u = *(const uint4*)(As + (wm + i * 16 + lm) * 32 + lq * 8);
            #pragma unroll
            for (int i = 0; i < 2; i++)
                bfx[i].u = *(const uint4*)(Bs + (wn + i * 16 + lm) * 32 + lq * 8);
            #pragma unroll
            for (int mi = 0; mi < 4; mi++)
                #pragma unroll
                for (int ni = 0; ni < 2; ni++)
                    acc[mi][ni] = __builtin_amdgcn_mfma_f32_16x16x32_bf16(
                        af[mi].s, bfx[ni].s, acc[mi][ni], 0, 0, 0);
        }
    }
#undef OSTAGE

    #pragma unroll
    for (int mi = 0; mi < 4; mi++) {
        int gr = m0 + wm + mi * 16 + lq * 4;
        #pragma unroll
        for (int ni = 0; ni < 2; ni++) {
            int gc = n0 + wn + ni * 16 + lm;
            float bv = bias[gc];
            #pragma unroll
            for (int r = 0; r < 4; r++)
                out[(size_t)(gr + r) * DD + gc] = acc[mi][ni][r] + bv;
        }
    }
}

// ---------------------------------------------------------------- launch
extern "C" void kernel_launch(void* const* d_in, const int* in_sizes, int n_in,
                              void* d_out, int out_size, void* d_ws, size_t ws_size,
                              hipStream_t stream) {
    const float* x     = (const float*)d_in[0];
    const float* w_qkv = (const float*)d_in[1];
    const float* w_out = (const float*)d_in[2];
    const float* b_out = (const float*)d_in[3];
    float* out = (float*)d_out;

    unsigned short* ws = (unsigned short*)d_ws;
    const size_t NX = (size_t)BB * SS * DD;        // 4,194,304
    unsigned short* x_bf    = ws;
    unsigned short* wqkv_bf = x_bf + NX;
    unsigned short* wout_bf = wqkv_bf + 3145728;
    unsigned short* q_buf   = wout_bf + 1048576;
    unsigned short* k_buf   = q_buf + NX;
    unsigned short* v_buf   = k_buf + NX;
    unsigned short* o_buf   = v_buf + NX;

    cvt_all<<<4096, 256, 0, stream>>>(x, w_qkv, w_out, x_bf, wqkv_bf, wout_bf);
    gemm_qkv<<<dim3(24, 32), 256, 0, stream>>>(x_bf, wqkv_bf, q_buf, k_buf, v_buf);
    attn<<<dim3(32, 32), 256, 0, stream>>>(q_buf, k_buf, v_buf, o_buf);
    gemm_out<<<dim3(16, 32), 256, 0, stream>>>(o_buf, wout_bf, b_out, out);
}

// Round 11
// 215.977 us; speedup vs baseline: 1.0020x; 1.0020x over previous
//
#include <hip/hip_runtime.h>
#include <cstdint>
#include <cstddef>

// Problem constants
#define BB 2
#define SS 2048
#define DD 1024
#define HH 16
#define HDIM 64
// Attention scale 1/sqrt(64)=0.125 and the exp->exp2 fold log2(e) are
// pre-multiplied into q at the gemm_qkv epilogue: 0.125*1.4426950 = 0.18033688.

typedef short bf16x8 __attribute__((ext_vector_type(8)));
typedef short bf16x4 __attribute__((ext_vector_type(4)));
typedef float f32x4 __attribute__((ext_vector_type(4)));

union U4S8 { uint4 u; bf16x8 s; };
union U2S4 { uint2 u; bf16x4 s; unsigned short h[4]; };

// 16x16x16 bf16 MFMA (K=16). __has_builtin(amdgcn) is FALSE in the host pass
// of HIP's dual compile — guard with __HIP_DEVICE_COMPILE__, dummy for host.
#if defined(__HIP_DEVICE_COMPILE__)
# if __has_builtin(__builtin_amdgcn_mfma_f32_16x16x16bf16_1k)
#  define MFMA_PV(a, b, c) __builtin_amdgcn_mfma_f32_16x16x16bf16_1k((a), (b), (c), 0, 0, 0)
# else
#  define MFMA_PV(a, b, c) __builtin_amdgcn_mfma_f32_16x16x16_bf16((a), (b), (c), 0, 0, 0)
# endif
#else
# define MFMA_PV(a, b, c) (c)
#endif

__device__ __forceinline__ unsigned short f2bf(float f) {
    union { float f; unsigned int u; } c; c.f = f;
    unsigned int u = c.u;
    unsigned int r = (u + 0x7FFFu + ((u >> 16) & 1u)) >> 16;  // RTNE
    return (unsigned short)r;
}
// cheap round (ties-away): 2 VALU ops. For P in [0,1] error ~2^-10 relative.
__device__ __forceinline__ unsigned short f2bf_fast(float f) {
    union { float f; unsigned int u; } c; c.f = f;
    return (unsigned short)((c.u + 0x8000u) >> 16);
}

// async global->LDS, 16B per lane. LDS dest must be wave-uniform base + lane*16.
__device__ __forceinline__ void async_cp16(const void* g, void* l) {
    __builtin_amdgcn_global_load_lds(
        (const __attribute__((address_space(1))) void*)g,
        (__attribute__((address_space(3))) void*)l, 16, 0, 0);
}

// ---------------------------------------------------------------- fp32 -> bf16
// One kernel for all three inputs (x:524288, w_qkv:393216, w_out:131072 uint4s).
__global__ __launch_bounds__(256) void cvt_all(
    const float* __restrict__ x, const float* __restrict__ wq,
    const float* __restrict__ wo,
    unsigned short* __restrict__ xb, unsigned short* __restrict__ wqb,
    unsigned short* __restrict__ wob) {
    int i = blockIdx.x * 256 + threadIdx.x;
    const float* in; unsigned short* out; int j;
    if (i < 524288)       { in = x;  out = xb;  j = i; }
    else if (i < 917504)  { in = wq; out = wqb; j = i - 524288; }
    else                  { in = wo; out = wob; j = i - 917504; }
    float4 a = ((const float4*)in)[2 * j];
    float4 b = ((const float4*)in)[2 * j + 1];
    union { uint4 u; unsigned short h[8]; } o;
    o.h[0] = f2bf(a.x); o.h[1] = f2bf(a.y); o.h[2] = f2bf(a.z); o.h[3] = f2bf(a.w);
    o.h[4] = f2bf(b.x); o.h[5] = f2bf(b.y); o.h[6] = f2bf(b.z); o.h[7] = f2bf(b.w);
    ((uint4*)out)[j] = o.u;
}

// ---------------------------------------------------------------- QKV GEMM
// C[m,e] = sum_d x[m,d] * w_qkv[e,d]  (NT). M=4096, N=3072, K=1024.
// 128x128 tile, BK=32, async dbuf staging (one barrier/BK). ALL epilogues now
// go through the aliased LDS gather buffer -> fully coalesced uint4 stores
// (q/k: no transpose, v: transposed). Round 10's 64-scalar-store q/k path was
// ~quarter-line write efficiency.
__global__ __launch_bounds__(256) void gemm_qkv(
    const unsigned short* __restrict__ A,   // x_bf   [4096][1024]
    const unsigned short* __restrict__ Bw,  // wqkv_bf[3072][1024]
    unsigned short* __restrict__ qb, unsigned short* __restrict__ kb,
    unsigned short* __restrict__ vb) {
    const int K = 1024;
    // staging: buf0 { As 4096 | Bs 4096 } buf1 { As | Bs } = 16384 shorts (32 KB)
    // epilogue alias: 4 waves x 64x72 = 18432 shorts (36 KB)
    __shared__ unsigned short smem[18432];
    int tid = threadIdx.x;
    int lane = tid & 63, wave = tid >> 6;
    int wm = (wave & 1) * 64, wn = (wave >> 1) * 64;
    int m0 = blockIdx.y * 128, n0 = blockIdx.x * 128;
    int lm = lane & 15, lq = lane >> 4;

    f32x4 acc[4][4] = {};

    int sdst = tid * 8;  // shorts; lane-contiguous dest
    const unsigned short* gA = A  + (size_t)(m0 + (tid >> 2)) * K + (tid & 3) * 8;
    const unsigned short* gB = Bw + (size_t)(n0 + (tid >> 2)) * K + (tid & 3) * 8;

#define GSTAGE(k0, buf) do {                                          \
        async_cp16(gA + (k0),          smem + (buf) + sdst);          \
        async_cp16(gA + 64 * K + (k0), smem + (buf) + 2048 + sdst);   \
        async_cp16(gB + (k0),          smem + (buf) + 4096 + sdst);   \
        async_cp16(gB + 64 * K + (k0), smem + (buf) + 6144 + sdst);   \
    } while (0)

    GSTAGE(0, 0);
    for (int k0 = 0; k0 < K; k0 += 64) {
        #pragma unroll
        for (int hf = 0; hf < 2; hf++) {
            int base = hf ? 8192 : 0;
            int obuf = hf ? 0 : 8192;
            __syncthreads();  // drains this buffer's loads; other buffer free
            int kn = k0 + 32 + hf * 32;
            if (kn < K) GSTAGE(kn, obuf);
            const unsigned short* As = smem + base;
            const unsigned short* Bs = smem + base + 4096;
            U4S8 af[4], bfx[4];
            #pragma unroll
            for (int i = 0; i < 4; i++) {
                af[i].u  = *(const uint4*)(As + (wm + i * 16 + lm) * 32 + lq * 8);
                bfx[i].u = *(const uint4*)(Bs + (wn + i * 16 + lm) * 32 + lq * 8);
            }
            #pragma unroll
            for (int mi = 0; mi < 4; mi++)
                #pragma unroll
                for (int ni = 0; ni < 4; ni++)
                    acc[mi][ni] = __builtin_amdgcn_mfma_f32_16x16x32_bf16(
                        af[mi].s, bfx[ni].s, acc[mi][ni], 0, 0, 0);
        }
    }
#undef GSTAGE
    __syncthreads();  // staging LDS done before epilogue alias reuse

    // Epilogue. C/D layout: col=lane&15, row=(lane>>4)*4+reg.
    // Wave's 64-col span = exactly one head (n0+wn is 64-aligned).
    unsigned short* Lw = smem + wave * 4608;  // 64 x 72
    int b = m0 >> 11;
    int s_base = (m0 + wm) & 2047;
    if (n0 < 1024) {
        // ---- v: transpose (store [B,H,HD,S]): Lw[hd][s]
        int h = (n0 + wn) >> 6;
        #pragma unroll
        for (int mi = 0; mi < 4; mi++)
            #pragma unroll
            for (int ni = 0; ni < 4; ni++)
                #pragma unroll
                for (int r = 0; r < 4; r++)
                    Lw[(ni * 16 + lm) * 72 + mi * 16 + lq * 4 + r] =
                        f2bf(acc[mi][ni][r]);
        __builtin_amdgcn_wave_barrier();
        unsigned short* vdst = vb + ((size_t)(b * HH + h) * HDIM) * SS + s_base;
        #pragma unroll
        for (int it = 0; it < 8; it++) {
            int hd = it * 8 + (lane >> 3);
            int so = (lane & 7) * 8;
            uint4 val = *(const uint4*)&Lw[hd * 72 + so];
            *(uint4*)(vdst + (size_t)hd * SS + so) = val;
        }
    } else {
        // ---- q/k: gather (store [B,H,S,HD]): Lw[s][hd], no transpose
        bool isq = n0 < 2048;
        unsigned short* dst = isq ? qb : kb;
        float scale = isq ? 0.18033688f : 1.0f;  // q: fold softmax scale * log2(e)
        int h = ((n0 + wn) >> 6) & 15;
        #pragma unroll
        for (int mi = 0; mi < 4; mi++)
            #pragma unroll
            for (int ni = 0; ni < 4; ni++)
                #pragma unroll
                for (int r = 0; r < 4; r++)
                    Lw[(mi * 16 + lq * 4 + r) * 72 + ni * 16 + lm] =
                        f2bf(acc[mi][ni][r] * scale);
        __builtin_amdgcn_wave_barrier();
        unsigned short* qdst =
            dst + ((size_t)(b * HH + h) * SS + s_base) * HDIM;
        #pragma unroll
        for (int it = 0; it < 8; it++) {
            int srw = it * 8 + (lane >> 3);
            int so = (lane & 7) * 8;
            uint4 val = *(const uint4*)&Lw[srw * 72 + so];
            *(uint4*)(qdst + (size_t)srw * HDIM + so) = val;
        }
    }
}

// ---------------------------------------------------------------- Flash attention
// Round-9 proven structure (74.3 µs): transposed register-P scheme
// (S^T = K·Q^T, O^T += V^T·P^T), async dbuf LDS (one barrier/tile),
// XOR-swizzled conflict-free reads, VALU lsum + final shuffle reduce.
// Round 10's ones-MFMA denominator REGRESSED (issue-saturation: moving work
// across pipes doesn't help when VALU+MFMA+DS sum to ~100%).
__global__ __launch_bounds__(256) void attn(
    const unsigned short* __restrict__ qb,  // [B,H,S,HD] pre-scaled (incl. log2e)
    const unsigned short* __restrict__ kb,  // [B,H,S,HD]
    const unsigned short* __restrict__ vb,  // [B,H,HD,S] (transposed)
    unsigned short* __restrict__ ob) {      // [B,S,D]
    int bh = blockIdx.y;
    int q0 = blockIdx.x * 64;
    int tid = threadIdx.x, lane = tid & 63, wave = tid >> 6;
    int lm = lane & 15, lq = lane >> 4;

    // Double buffer: [bufA: Kt 64x64 | Vt 64x64][bufB: same] = 32 KB, no padding.
    __shared__ unsigned short smem[4 * 4096];

    const unsigned short* qg = qb + (size_t)bh * SS * HDIM;
    const unsigned short* kg = kb + (size_t)bh * SS * HDIM;
    const unsigned short* vg = vb + (size_t)bh * HDIM * SS;

    // Q fragments, B-operand of S^T: n=q=lane&15, k=hd=lq*8+j
    U4S8 qf[2];
    #pragma unroll
    for (int ks = 0; ks < 2; ks++)
        qf[ks].u = *(const uint4*)(
            qg + (size_t)(q0 + wave * 16 + lm) * HDIM + ks * 32 + lq * 8);

    f32x4 oacc[4] = {};   // O^T[hd-tile]: col=q=lm, row=hd=lq*4+r (+16*mi2)
    float lsum = 0.f;     // per-lane partial over this lane's k subset

    // ---- loop-invariant swizzled LDS read indices (shorts)
    int lm7 = lm & 7;
    int kidx = lm * 64 + 8 * (lq ^ lm7);          // kf chunk lq (hd 0..31)
    int vidx[4];
    #pragma unroll
    for (int kc = 0; kc < 4; kc++)
        vidx[kc] = lm * 64 + 8 * (((kc << 1) | (lq >> 1)) ^ lm7) + (lq & 1) * 4;

    // ---- staging indices (async: dest = wave-uniform base + lane*16B)
    int srow = tid >> 3;                  // 0..31
    int scl  = (tid & 7) ^ (srow & 7);    // logical chunk for physical chunk tid&7
    int sdst = tid * 8;                   // shorts
    const unsigned short* ksrc0 = kg + (size_t)srow * HDIM + scl * 8;
    const unsigned short* vsrc0 = vg + (size_t)srow * SS + scl * 8;

    #define STAGE(ktile, buf)                                                   \
        do {                                                                    \
            int _o = (ktile) * 64;                                              \
            async_cp16(ksrc0 + (size_t)_o * HDIM,        smem + (buf) + sdst);         \
            async_cp16(ksrc0 + (size_t)(_o + 32) * HDIM, smem + (buf) + 2048 + sdst);  \
            async_cp16(vsrc0 + _o,                       smem + (buf) + 4096 + sdst);  \
            async_cp16(vsrc0 + (size_t)32 * SS + _o,     smem + (buf) + 6144 + sdst);  \
        } while (0)

    STAGE(0, 0);

    for (int kt = 0; kt < SS / 64; kt += 2) {
        #pragma unroll
        for (int hf = 0; hf < 2; hf++) {
            int base = hf ? 8192 : 0;       // compute buffer
            int obuf = hf ? 0 : 8192;       // stage target (other buffer)
            __syncthreads();  // drains vmcnt: this buffer's loads landed
            STAGE((kt + 1 + hf) & 31, obuf);  // wraps harmlessly on last iter

            // ---- S^T then P^T = 2^(S^T) in regs (C-layout == PV B-layout)
            U2S4 pb[4];
            #pragma unroll
            for (int mi = 0; mi < 4; mi++) {
                U4S8 kf0, kf1;
                kf0.u = *(const uint4*)(smem + base + mi * 1024 + kidx);
                kf1.u = *(const uint4*)(smem + base + mi * 1024 + (kidx ^ 32));
                f32x4 sa = {};
                sa = __builtin_amdgcn_mfma_f32_16x16x32_bf16(kf0.s, qf[0].s, sa, 0, 0, 0);
                sa = __builtin_amdgcn_mfma_f32_16x16x32_bf16(kf1.s, qf[1].s, sa, 0, 0, 0);
                #pragma unroll
                for (int r = 0; r < 4; r++) {
                    float p = exp2f(sa[r]);
                    lsum += p;
                    pb[mi].h[r] = f2bf_fast(p);
                }
            }

            // ---- O^T[hd][q] += V^T[hd][k] * P^T[k][q]  (16x16x16)
            #pragma unroll
            for (int mi2 = 0; mi2 < 4; mi2++) {
                #pragma unroll
                for (int kc = 0; kc < 4; kc++) {
                    U2S4 vf;
                    vf.u = *(const uint2*)(smem + base + 4096 + mi2 * 1024 + vidx[kc]);
                    oacc[mi2] = MFMA_PV(vf.s, pb[kc].s, oacc[mi2]);
                }
            }
        }
    }
    #undef STAGE

    // ---- row sum: lanes lm, lm+16, lm+32, lm+48 hold disjoint k partials
    float s = lsum;
    s += __shfl_xor(s, 16);
    s += __shfl_xor(s, 32);
    float inv = 1.f / s;

    // ---- transpose O^T back via smem, store coalesced bf16 [B,S,D]
    __syncthreads();  // all compute done; drains the wrapped stray loads
    unsigned short* Ow = smem + wave * (16 * 72);
    #pragma unroll
    for (int mi2 = 0; mi2 < 4; mi2++) {
        U2S4 t;
        #pragma unroll
        for (int r = 0; r < 4; r++)
            t.h[r] = f2bf(oacc[mi2][r] * inv);
        *(uint2*)&Ow[lm * 72 + mi2 * 16 + lq * 4] = t.u;
    }
    __builtin_amdgcn_wave_barrier();  // Ow wave-local
    int b = bh >> 4, h = bh & 15;
    #pragma unroll
    for (int it = 0; it < 2; it++) {
        int q  = it * 8 + (lane >> 3);
        int off = (lane & 7) * 8;
        uint4 val = *(const uint4*)&Ow[q * 72 + off];
        int srw = q0 + wave * 16 + q;
        *(uint4*)(ob + (size_t)(b * SS + srw) * DD + h * 64 + off) = val;
    }
}

// ---------------------------------------------------------------- Output GEMM
// out[m,e] = sum_d o[m,d] * w_out[e,d] + b_out[e].  M=4096, N=1024, K=1024.
// 128x64 tile -> 512 blocks (2/CU); async dbuf staging, one barrier per BK.
__global__ __launch_bounds__(256) void gemm_out(
    const unsigned short* __restrict__ A,   // o_bf   [4096][1024]
    const unsigned short* __restrict__ Bw,  // wout_bf[1024][1024]
    const float* __restrict__ bias, float* __restrict__ out) {
    const int K = 1024;
    // buf { As 4096 | Bs 2048 } x2 = 12288 shorts (24 KB)
    __shared__ unsigned short smem[12288];
    int tid = threadIdx.x;
    int lane = tid & 63, wave = tid >> 6;
    int wm = (wave & 1) * 64, wn = (wave >> 1) * 32;
    int m0 = blockIdx.y * 128, n0 = blockIdx.x * 64;
    int lm = lane & 15, lq = lane >> 4;

    f32x4 acc[4][2] = {};

    int sdst = tid * 8;
    const unsigned short* gA = A  + (size_t)(m0 + (tid >> 2)) * K + (tid & 3) * 8;
    const unsigned short* gB = Bw + (size_t)(n0 + (tid >> 2)) * K + (tid & 3) * 8;

#define OSTAGE(k0, buf) do {                                          \
        async_cp16(gA + (k0),          smem + (buf) + sdst);          \
        async_cp16(gA + 64 * K + (k0), smem + (buf) + 2048 + sdst);   \
        async_cp16(gB + (k0),          smem + (buf) + 4096 + sdst);   \
    } while (0)

    OSTAGE(0, 0);
    for (int k0 = 0; k0 < K; k0 += 64) {
        #pragma unroll
        for (int hf = 0; hf < 2; hf++) {
            int base = hf ? 6144 : 0;
            int obuf = hf ? 0 : 6144;
            __syncthreads();
            int kn = k0 + 32 + hf * 32;
            if (kn < K) OSTAGE(kn, obuf);
            const unsigned short* As = smem + base;
            const unsigned short* Bs = smem + base + 4096;
            U4S8 af[4], bfx[2];
            #pragma unroll
            for (int i = 0; i < 4; i++)
                af[i].u = *(const uint4*)(As + (wm + i * 16 + lm) * 32 + lq * 8);
            #pragma unroll
            for (int i = 0; i < 2; i++)
                bfx[i].u = *(const uint4*)(Bs + (wn + i * 16 + lm) * 32 + lq * 8);
            #pragma unroll
            for (int mi = 0; mi < 4; mi++)
                #pragma unroll
                for (int ni = 0; ni < 2; ni++)
                    acc[mi][ni] = __builtin_amdgcn_mfma_f32_16x16x32_bf16(
                        af[mi].s, bfx[ni].s, acc[mi][ni], 0, 0, 0);
        }
    }
#undef OSTAGE

    #pragma unroll
    for (int mi = 0; mi < 4; mi++) {
        int gr = m0 + wm + mi * 16 + lq * 4;
        #pragma unroll
        for (int ni = 0; ni < 2; ni++) {
            int gc = n0 + wn + ni * 16 + lm;
            float bv = bias[gc];
            #pragma unroll
            for (int r = 0; r < 4; r++)
                out[(size_t)(gr + r) * DD + gc] = acc[mi][ni][r] + bv;
        }
    }
}

// ---------------------------------------------------------------- launch
extern "C" void kernel_launch(void* const* d_in, const int* in_sizes, int n_in,
                              void* d_out, int out_size, void* d_ws, size_t ws_size,
                              hipStream_t stream) {
    const float* x     = (const float*)d_in[0];
    const float* w_qkv = (const float*)d_in[1];
    const float* w_out = (const float*)d_in[2];
    const float* b_out = (const float*)d_in[3];
    float* out = (float*)d_out;

    unsigned short* ws = (unsigned short*)d_ws;
    const size_t NX = (size_t)BB * SS * DD;        // 4,194,304
    unsigned short* x_bf    = ws;
    unsigned short* wqkv_bf = x_bf + NX;
    unsigned short* wout_bf = wqkv_bf + 3145728;
    unsigned short* q_buf   = wout_bf + 1048576;
    unsigned short* k_buf   = q_buf + NX;
    unsigned short* v_buf   = k_buf + NX;
    unsigned short* o_buf   = v_buf + NX;

    cvt_all<<<4096, 256, 0, stream>>>(x, w_qkv, w_out, x_bf, wqkv_bf, wout_bf);
    gemm_qkv<<<dim3(24, 32), 256, 0, stream>>>(x_bf, wqkv_bf, q_buf, k_buf, v_buf);
    attn<<<dim3(32, 32), 256, 0, stream>>>(q_buf, k_buf, v_buf, o_buf);
    gemm_out<<<dim3(16, 32), 256, 0, stream>>>(o_buf, wout_bf, b_out, out);
}

// Round 12
// 206.624 us; speedup vs baseline: 1.0473x; 1.0453x over previous
//
#include <hip/hip_runtime.h>
#include <cstdint>
#include <cstddef>

// Problem constants
#define BB 2
#define SS 2048
#define DD 1024
#define HH 16
#define HDIM 64
// Attention scale 1/sqrt(64)=0.125 and the exp->exp2 fold log2(e) are
// pre-multiplied into q at the gemm_qkv epilogue: 0.125*1.4426950 = 0.18033688.

typedef short bf16x8 __attribute__((ext_vector_type(8)));
typedef short bf16x4 __attribute__((ext_vector_type(4)));
typedef float f32x4 __attribute__((ext_vector_type(4)));
typedef float f32x2 __attribute__((ext_vector_type(2)));

union U4S8 { uint4 u; bf16x8 s; };
union U2S4 { uint2 u; bf16x4 s; unsigned short h[4]; };

// 16x16x16 bf16 MFMA (K=16). __has_builtin(amdgcn) is FALSE in the host pass
// of HIP's dual compile — guard with __HIP_DEVICE_COMPILE__, dummy for host.
#if defined(__HIP_DEVICE_COMPILE__)
# if __has_builtin(__builtin_amdgcn_mfma_f32_16x16x16bf16_1k)
#  define MFMA_PV(a, b, c) __builtin_amdgcn_mfma_f32_16x16x16bf16_1k((a), (b), (c), 0, 0, 0)
# else
#  define MFMA_PV(a, b, c) __builtin_amdgcn_mfma_f32_16x16x16_bf16((a), (b), (c), 0, 0, 0)
# endif
# if __has_builtin(__builtin_amdgcn_exp2f)
#  define EXP2(x) __builtin_amdgcn_exp2f(x)   // bare v_exp_f32, no libm envelope
# else
#  define EXP2(x) exp2f(x)
# endif
#else
# define MFMA_PV(a, b, c) (c)
# define EXP2(x) exp2f(x)
#endif

__device__ __forceinline__ unsigned short f2bf(float f) {
    union { float f; unsigned int u; } c; c.f = f;
    unsigned int u = c.u;
    unsigned int r = (u + 0x7FFFu + ((u >> 16) & 1u)) >> 16;  // RTNE
    return (unsigned short)r;
}

// async global->LDS, 16B per lane. LDS dest must be wave-uniform base + lane*16.
__device__ __forceinline__ void async_cp16(const void* g, void* l) {
    __builtin_amdgcn_global_load_lds(
        (const __attribute__((address_space(1))) void*)g,
        (__attribute__((address_space(3))) void*)l, 16, 0, 0);
}

// ---------------------------------------------------------------- fp32 -> bf16
// One kernel for all three inputs (x:524288, w_qkv:393216, w_out:131072 uint4s).
__global__ __launch_bounds__(256) void cvt_all(
    const float* __restrict__ x, const float* __restrict__ wq,
    const float* __restrict__ wo,
    unsigned short* __restrict__ xb, unsigned short* __restrict__ wqb,
    unsigned short* __restrict__ wob) {
    int i = blockIdx.x * 256 + threadIdx.x;
    const float* in; unsigned short* out; int j;
    if (i < 524288)       { in = x;  out = xb;  j = i; }
    else if (i < 917504)  { in = wq; out = wqb; j = i - 524288; }
    else                  { in = wo; out = wob; j = i - 917504; }
    float4 a = ((const float4*)in)[2 * j];
    float4 b = ((const float4*)in)[2 * j + 1];
    union { uint4 u; unsigned short h[8]; } o;
    o.h[0] = f2bf(a.x); o.h[1] = f2bf(a.y); o.h[2] = f2bf(a.z); o.h[3] = f2bf(a.w);
    o.h[4] = f2bf(b.x); o.h[5] = f2bf(b.y); o.h[6] = f2bf(b.z); o.h[7] = f2bf(b.w);
    ((uint4*)out)[j] = o.u;
}

// ---------------------------------------------------------------- QKV GEMM
// C[m,e] = sum_d x[m,d] * w_qkv[e,d]  (NT). M=4096, N=3072, K=1024.
// 128x128 tile, BK=32, async dbuf staging (one barrier/BK). Epilogues go
// through the aliased LDS gather buffer -> coalesced uint4 stores.
__global__ __launch_bounds__(256) void gemm_qkv(
    const unsigned short* __restrict__ A,   // x_bf   [4096][1024]
    const unsigned short* __restrict__ Bw,  // wqkv_bf[3072][1024]
    unsigned short* __restrict__ qb, unsigned short* __restrict__ kb,
    unsigned short* __restrict__ vb) {
    const int K = 1024;
    // staging: buf0 { As 4096 | Bs 4096 } buf1 { As | Bs } = 16384 shorts (32 KB)
    // epilogue alias: 4 waves x 64x72 = 18432 shorts (36 KB)
    __shared__ unsigned short smem[18432];
    int tid = threadIdx.x;
    int lane = tid & 63, wave = tid >> 6;
    int wm = (wave & 1) * 64, wn = (wave >> 1) * 64;
    int m0 = blockIdx.y * 128, n0 = blockIdx.x * 128;
    int lm = lane & 15, lq = lane >> 4;

    f32x4 acc[4][4] = {};

    int sdst = tid * 8;  // shorts; lane-contiguous dest
    const unsigned short* gA = A  + (size_t)(m0 + (tid >> 2)) * K + (tid & 3) * 8;
    const unsigned short* gB = Bw + (size_t)(n0 + (tid >> 2)) * K + (tid & 3) * 8;

#define GSTAGE(k0, buf) do {                                          \
        async_cp16(gA + (k0),          smem + (buf) + sdst);          \
        async_cp16(gA + 64 * K + (k0), smem + (buf) + 2048 + sdst);   \
        async_cp16(gB + (k0),          smem + (buf) + 4096 + sdst);   \
        async_cp16(gB + 64 * K + (k0), smem + (buf) + 6144 + sdst);   \
    } while (0)

    GSTAGE(0, 0);
    for (int k0 = 0; k0 < K; k0 += 64) {
        #pragma unroll
        for (int hf = 0; hf < 2; hf++) {
            int base = hf ? 8192 : 0;
            int obuf = hf ? 0 : 8192;
            __syncthreads();  // drains this buffer's loads; other buffer free
            int kn = k0 + 32 + hf * 32;
            if (kn < K) GSTAGE(kn, obuf);
            const unsigned short* As = smem + base;
            const unsigned short* Bs = smem + base + 4096;
            U4S8 af[4], bfx[4];
            #pragma unroll
            for (int i = 0; i < 4; i++) {
                af[i].u  = *(const uint4*)(As + (wm + i * 16 + lm) * 32 + lq * 8);
                bfx[i].u = *(const uint4*)(Bs + (wn + i * 16 + lm) * 32 + lq * 8);
            }
            #pragma unroll
            for (int mi = 0; mi < 4; mi++)
                #pragma unroll
                for (int ni = 0; ni < 4; ni++)
                    acc[mi][ni] = __builtin_amdgcn_mfma_f32_16x16x32_bf16(
                        af[mi].s, bfx[ni].s, acc[mi][ni], 0, 0, 0);
        }
    }
#undef GSTAGE
    __syncthreads();  // staging LDS done before epilogue alias reuse

    // Epilogue. C/D layout: col=lane&15, row=(lane>>4)*4+reg.
    unsigned short* Lw = smem + wave * 4608;  // 64 x 72
    int b = m0 >> 11;
    int s_base = (m0 + wm) & 2047;
    if (n0 < 1024) {
        // ---- v: transpose (store [B,H,HD,S]): Lw[hd][s]
        int h = (n0 + wn) >> 6;
        #pragma unroll
        for (int mi = 0; mi < 4; mi++)
            #pragma unroll
            for (int ni = 0; ni < 4; ni++)
                #pragma unroll
                for (int r = 0; r < 4; r++)
                    Lw[(ni * 16 + lm) * 72 + mi * 16 + lq * 4 + r] =
                        f2bf(acc[mi][ni][r]);
        __builtin_amdgcn_wave_barrier();
        unsigned short* vdst = vb + ((size_t)(b * HH + h) * HDIM) * SS + s_base;
        #pragma unroll
        for (int it = 0; it < 8; it++) {
            int hd = it * 8 + (lane >> 3);
            int so = (lane & 7) * 8;
            uint4 val = *(const uint4*)&Lw[hd * 72 + so];
            *(uint4*)(vdst + (size_t)hd * SS + so) = val;
        }
    } else {
        // ---- q/k: gather (store [B,H,S,HD]): Lw[s][hd], no transpose
        bool isq = n0 < 2048;
        unsigned short* dst = isq ? qb : kb;
        float scale = isq ? 0.18033688f : 1.0f;  // q: fold softmax scale * log2(e)
        int h = ((n0 + wn) >> 6) & 15;
        #pragma unroll
        for (int mi = 0; mi < 4; mi++)
            #pragma unroll
            for (int ni = 0; ni < 4; ni++)
                #pragma unroll
                for (int r = 0; r < 4; r++)
                    Lw[(mi * 16 + lq * 4 + r) * 72 + ni * 16 + lm] =
                        f2bf(acc[mi][ni][r] * scale);
        __builtin_amdgcn_wave_barrier();
        unsigned short* qdst =
            dst + ((size_t)(b * HH + h) * SS + s_base) * HDIM;
        #pragma unroll
        for (int it = 0; it < 8; it++) {
            int srw = it * 8 + (lane >> 3);
            int so = (lane & 7) * 8;
            uint4 val = *(const uint4*)&Lw[srw * 72 + so];
            *(uint4*)(qdst + (size_t)srw * HDIM + so) = val;
        }
    }
}

// ---------------------------------------------------------------- Flash attention
// r9 structure (transposed register-P, async dbuf, XOR swizzle) + r12 VALU diet:
//  * bare v_exp_f32 via __builtin_amdgcn_exp2f (libm envelope was ~6 instr/exp)
//  * v_perm bf16 pair packing (validated correct in r10)
//  * pointer-increment staging (no per-tile mul / wrap mask; final prefetch
//    over-reads into the adjacent allocated ws buffer — data unused)
//  * lsum as float2 -> v_pk_add_f32
__global__ __launch_bounds__(256) void attn(
    const unsigned short* __restrict__ qb,  // [B,H,S,HD] pre-scaled (incl. log2e)
    const unsigned short* __restrict__ kb,  // [B,H,S,HD]
    const unsigned short* __restrict__ vb,  // [B,H,HD,S] (transposed)
    unsigned short* __restrict__ ob) {      // [B,S,D]
    int bh = blockIdx.y;
    int q0 = blockIdx.x * 64;
    int tid = threadIdx.x, lane = tid & 63, wave = tid >> 6;
    int lm = lane & 15, lq = lane >> 4;

    // Double buffer: [bufA: Kt 64x64 | Vt 64x64][bufB: same] = 32 KB, no padding.
    __shared__ unsigned short smem[4 * 4096];

    const unsigned short* qg = qb + (size_t)bh * SS * HDIM;
    const unsigned short* kg = kb + (size_t)bh * SS * HDIM;
    const unsigned short* vg = vb + (size_t)bh * HDIM * SS;

    // Q fragments, B-operand of S^T: n=q=lane&15, k=hd=lq*8+j
    U4S8 qf[2];
    #pragma unroll
    for (int ks = 0; ks < 2; ks++)
        qf[ks].u = *(const uint4*)(
            qg + (size_t)(q0 + wave * 16 + lm) * HDIM + ks * 32 + lq * 8);

    f32x4 oacc[4] = {};    // O^T[hd-tile]: col=q=lm, row=hd=lq*4+r (+16*mi2)
    f32x2 lsum2 = {0.f, 0.f};  // per-lane partial sums (packed adds)

    // ---- loop-invariant swizzled LDS read indices (shorts)
    int lm7 = lm & 7;
    int kidx = lm * 64 + 8 * (lq ^ lm7);          // kf chunk lq (hd 0..31)
    int vidx[4];
    #pragma unroll
    for (int kc = 0; kc < 4; kc++)
        vidx[kc] = lm * 64 + 8 * (((kc << 1) | (lq >> 1)) ^ lm7) + (lq & 1) * 4;

    // ---- staging pointers (async: dest = wave-uniform base + lane*16B)
    int srow = tid >> 3;                  // 0..31
    int scl  = (tid & 7) ^ (srow & 7);    // logical chunk for physical chunk tid&7
    int sdst = tid * 8;                   // shorts
    const unsigned short* kptr = kg + (size_t)srow * HDIM + scl * 8;
    const unsigned short* vptr = vg + (size_t)srow * SS + scl * 8;

    // stage CURRENT pointer tile into buf, then advance pointers one tile.
    #define STAGE(buf)                                                         \
        do {                                                                   \
            async_cp16(kptr,             smem + (buf) + sdst);                 \
            async_cp16(kptr + 32 * HDIM, smem + (buf) + 2048 + sdst);          \
            async_cp16(vptr,             smem + (buf) + 4096 + sdst);          \
            async_cp16(vptr + 32 * SS,   smem + (buf) + 6144 + sdst);          \
            kptr += 64 * HDIM; vptr += 64;                                     \
        } while (0)

    STAGE(0);

    for (int kt = 0; kt < SS / 64; kt += 2) {
        #pragma unroll
        for (int hf = 0; hf < 2; hf++) {
            int base = hf ? 8192 : 0;       // compute buffer
            int obuf = hf ? 0 : 8192;       // stage target (other buffer)
            __syncthreads();  // drains vmcnt: this buffer's loads landed
            STAGE(obuf);  // last iteration over-reads one tile into the
                          // adjacent ws buffer (allocated; data unused)

            // ---- S^T then P^T = 2^(S^T) in regs (C-layout == PV B-layout)
            U2S4 pb[4];
            #pragma unroll
            for (int mi = 0; mi < 4; mi++) {
                U4S8 kf0, kf1;
                kf0.u = *(const uint4*)(smem + base + mi * 1024 + kidx);
                kf1.u = *(const uint4*)(smem + base + mi * 1024 + (kidx ^ 32));
                f32x4 sa = {};
                sa = __builtin_amdgcn_mfma_f32_16x16x32_bf16(kf0.s, qf[0].s, sa, 0, 0, 0);
                sa = __builtin_amdgcn_mfma_f32_16x16x32_bf16(kf1.s, qf[1].s, sa, 0, 0, 0);
                float p0 = EXP2(sa[0]);
                float p1 = EXP2(sa[1]);
                float p2 = EXP2(sa[2]);
                float p3 = EXP2(sa[3]);
                f32x2 a01; a01[0] = p0; a01[1] = p1;
                f32x2 a23; a23[0] = p2; a23[1] = p3;
                lsum2 += a01;
                lsum2 += a23;
                unsigned int b0 = __float_as_uint(p0) + 0x8000u;  // ties-away rnd
                unsigned int b1 = __float_as_uint(p1) + 0x8000u;
                unsigned int b2 = __float_as_uint(p2) + 0x8000u;
                unsigned int b3 = __float_as_uint(p3) + 0x8000u;
                pb[mi].u.x = __builtin_amdgcn_perm(b1, b0, 0x07060302u);
                pb[mi].u.y = __builtin_amdgcn_perm(b3, b2, 0x07060302u);
            }

            // ---- O^T[hd][q] += V^T[hd][k] * P^T[k][q]  (16x16x16)
            #pragma unroll
            for (int mi2 = 0; mi2 < 4; mi2++) {
                #pragma unroll
                for (int kc = 0; kc < 4; kc++) {
                    U2S4 vf;
                    vf.u = *(const uint2*)(smem + base + 4096 + mi2 * 1024 + vidx[kc]);
                    oacc[mi2] = MFMA_PV(vf.s, pb[kc].s, oacc[mi2]);
                }
            }
        }
    }
    #undef STAGE

    // ---- row sum: lanes lm, lm+16, lm+32, lm+48 hold disjoint k partials
    float s = lsum2[0] + lsum2[1];
    s += __shfl_xor(s, 16);
    s += __shfl_xor(s, 32);
    float inv = 1.f / s;

    // ---- transpose O^T back via smem, store coalesced bf16 [B,S,D]
    __syncthreads();  // all compute done; drains the stray over-read loads
    unsigned short* Ow = smem + wave * (16 * 72);
    #pragma unroll
    for (int mi2 = 0; mi2 < 4; mi2++) {
        U2S4 t;
        #pragma unroll
        for (int r = 0; r < 4; r++)
            t.h[r] = f2bf(oacc[mi2][r] * inv);
        *(uint2*)&Ow[lm * 72 + mi2 * 16 + lq * 4] = t.u;
    }
    __builtin_amdgcn_wave_barrier();  // Ow wave-local
    int b = bh >> 4, h = bh & 15;
    #pragma unroll
    for (int it = 0; it < 2; it++) {
        int q  = it * 8 + (lane >> 3);
        int off = (lane & 7) * 8;
        uint4 val = *(const uint4*)&Ow[q * 72 + off];
        int srw = q0 + wave * 16 + q;
        *(uint4*)(ob + (size_t)(b * SS + srw) * DD + h * 64 + off) = val;
    }
}

// ---------------------------------------------------------------- Output GEMM
// out[m,e] = sum_d o[m,d] * w_out[e,d] + b_out[e].  M=4096, N=1024, K=1024.
// 128x64 tile -> 512 blocks (2/CU); async dbuf staging, one barrier per BK.
__global__ __launch_bounds__(256) void gemm_out(
    const unsigned short* __restrict__ A,   // o_bf   [4096][1024]
    const unsigned short* __restrict__ Bw,  // wout_bf[1024][1024]
    const float* __restrict__ bias, float* __restrict__ out) {
    const int K = 1024;
    // buf { As 4096 | Bs 2048 } x2 = 12288 shorts (24 KB)
    __shared__ unsigned short smem[12288];
    int tid = threadIdx.x;
    int lane = tid & 63, wave = tid >> 6;
    int wm = (wave & 1) * 64, wn = (wave >> 1) * 32;
    int m0 = blockIdx.y * 128, n0 = blockIdx.x * 64;
    int lm = lane & 15, lq = lane >> 4;

    f32x4 acc[4][2] = {};

    int sdst = tid * 8;
    const unsigned short* gA = A  + (size_t)(m0 + (tid >> 2)) * K + (tid & 3) * 8;
    const unsigned short* gB = Bw + (size_t)(n0 + (tid >> 2)) * K + (tid & 3) * 8;

#define OSTAGE(k0, buf) do {                                          \
        async_cp16(gA + (k0),          smem + (buf) + sdst);          \
        async_cp16(gA + 64 * K + (k0), smem + (buf) + 2048 + sdst);   \
        async_cp16(gB + (k0),          smem + (buf) + 4096 + sdst);   \
    } while (0)

    OSTAGE(0, 0);
    for (int k0 = 0; k0 < K; k0 += 64) {
        #pragma unroll
        for (int hf = 0; hf < 2; hf++) {
            int base = hf ? 6144 : 0;
            int obuf = hf ? 0 : 6144;
            __syncthreads();
            int kn = k0 + 32 + hf * 32;
            if (kn < K) OSTAGE(kn, obuf);
            const unsigned short* As = smem + base;
            const unsigned short* Bs = smem + base + 4096;
            U4S8 af[4], bfx[2];
            #pragma unroll
            for (int i = 0; i < 4; i++)
                af[i].u = *(const uint4*)(As + (wm + i * 16 + lm) * 32 + lq * 8);
            #pragma unroll
            for (int i = 0; i < 2; i++)
                bfx[i].u = *(const uint4*)(Bs + (wn + i * 16 + lm) * 32 + lq * 8);
            #pragma unroll
            for (int mi = 0; mi < 4; mi++)
                #pragma unroll
                for (int ni = 0; ni < 2; ni++)
                    acc[mi][ni] = __builtin_amdgcn_mfma_f32_16x16x32_bf16(
                        af[mi].s, bfx[ni].s, acc[mi][ni], 0, 0, 0);
        }
    }
#undef OSTAGE

    #pragma unroll
    for (int mi = 0; mi < 4; mi++) {
        int gr = m0 + wm + mi * 16 + lq * 4;
        #pragma unroll
        for (int ni = 0; ni < 2; ni++) {
            int gc = n0 + wn + ni * 16 + lm;
            float bv = bias[gc];
            #pragma unroll
            for (int r = 0; r < 4; r++)
                out[(size_t)(gr + r) * DD + gc] = acc[mi][ni][r] + bv;
        }
    }
}

// ---------------------------------------------------------------- launch
extern "C" void kernel_launch(void* const* d_in, const int* in_sizes, int n_in,
                              void* d_out, int out_size, void* d_ws, size_t ws_size,
                              hipStream_t stream) {
    const float* x     = (const float*)d_in[0];
    const float* w_qkv = (const float*)d_in[1];
    const float* w_out = (const float*)d_in[2];
    const float* b_out = (const float*)d_in[3];
    float* out = (float*)d_out;

    unsigned short* ws = (unsigned short*)d_ws;
    const size_t NX = (size_t)BB * SS * DD;        // 4,194,304
    unsigned short* x_bf    = ws;
    unsigned short* wqkv_bf = x_bf + NX;
    unsigned short* wout_bf = wqkv_bf + 3145728;
    unsigned short* q_buf   = wout_bf + 1048576;
    unsigned short* k_buf   = q_buf + NX;
    unsigned short* v_buf   = k_buf + NX;
    unsigned short* o_buf   = v_buf + NX;

    cvt_all<<<4096, 256, 0, stream>>>(x, w_qkv, w_out, x_bf, wqkv_bf, wout_bf);
    gemm_qkv<<<dim3(24, 32), 256, 0, stream>>>(x_bf, wqkv_bf, q_buf, k_buf, v_buf);
    attn<<<dim3(32, 32), 256, 0, stream>>>(q_buf, k_buf, v_buf, o_buf);
    gemm_out<<<dim3(16, 32), 256, 0, stream>>>(o_buf, wout_bf, b_out, out);
}

// Round 13
// 204.954 us; speedup vs baseline: 1.0558x; 1.0081x over previous
//
#include <hip/hip_runtime.h>
#include <cstdint>
#include <cstddef>

// Problem constants
#define BB 2
#define SS 2048
#define DD 1024
#define HH 16
#define HDIM 64
// Attention scale 1/sqrt(64)=0.125 and the exp->exp2 fold log2(e) are
// pre-multiplied into q at the gemm_qkv epilogue: 0.125*1.4426950 = 0.18033688.

typedef short bf16x8 __attribute__((ext_vector_type(8)));
typedef short bf16x4 __attribute__((ext_vector_type(4)));
typedef float f32x4 __attribute__((ext_vector_type(4)));
typedef float f32x2 __attribute__((ext_vector_type(2)));

union U4S8 { uint4 u; bf16x8 s; };
union U2S4 { uint2 u; bf16x4 s; unsigned short h[4]; };

// 16x16x16 bf16 MFMA (K=16). __has_builtin(amdgcn) is FALSE in the host pass
// of HIP's dual compile — guard with __HIP_DEVICE_COMPILE__, dummy for host.
#if defined(__HIP_DEVICE_COMPILE__)
# if __has_builtin(__builtin_amdgcn_mfma_f32_16x16x16bf16_1k)
#  define MFMA_PV(a, b, c) __builtin_amdgcn_mfma_f32_16x16x16bf16_1k((a), (b), (c), 0, 0, 0)
# else
#  define MFMA_PV(a, b, c) __builtin_amdgcn_mfma_f32_16x16x16_bf16((a), (b), (c), 0, 0, 0)
# endif
# if __has_builtin(__builtin_amdgcn_exp2f)
#  define EXP2(x) __builtin_amdgcn_exp2f(x)   // bare v_exp_f32, no libm envelope
# else
#  define EXP2(x) exp2f(x)
# endif
#else
# define MFMA_PV(a, b, c) (c)
# define EXP2(x) exp2f(x)
#endif

__device__ __forceinline__ unsigned short f2bf(float f) {
    union { float f; unsigned int u; } c; c.f = f;
    unsigned int u = c.u;
    unsigned int r = (u + 0x7FFFu + ((u >> 16) & 1u)) >> 16;  // RTNE
    return (unsigned short)r;
}

// async global->LDS, 16B per lane. LDS dest must be wave-uniform base + lane*16.
__device__ __forceinline__ void async_cp16(const void* g, void* l) {
    __builtin_amdgcn_global_load_lds(
        (const __attribute__((address_space(1))) void*)g,
        (__attribute__((address_space(3))) void*)l, 16, 0, 0);
}

// ---------------------------------------------------------------- fp32 -> bf16
// One kernel for all three inputs (x:524288, w_qkv:393216, w_out:131072 uint4s).
__global__ __launch_bounds__(256) void cvt_all(
    const float* __restrict__ x, const float* __restrict__ wq,
    const float* __restrict__ wo,
    unsigned short* __restrict__ xb, unsigned short* __restrict__ wqb,
    unsigned short* __restrict__ wob) {
    int i = blockIdx.x * 256 + threadIdx.x;
    const float* in; unsigned short* out; int j;
    if (i < 524288)       { in = x;  out = xb;  j = i; }
    else if (i < 917504)  { in = wq; out = wqb; j = i - 524288; }
    else                  { in = wo; out = wob; j = i - 917504; }
    float4 a = ((const float4*)in)[2 * j];
    float4 b = ((const float4*)in)[2 * j + 1];
    union { uint4 u; unsigned short h[8]; } o;
    o.h[0] = f2bf(a.x); o.h[1] = f2bf(a.y); o.h[2] = f2bf(a.z); o.h[3] = f2bf(a.w);
    o.h[4] = f2bf(b.x); o.h[5] = f2bf(b.y); o.h[6] = f2bf(b.z); o.h[7] = f2bf(b.w);
    ((uint4*)out)[j] = o.u;
}

// ---------------------------------------------------------------- QKV GEMM
// C[m,e] = sum_d x[m,d] * w_qkv[e,d]  (NT). M=4096, N=3072, K=1024.
// 128x128 tile, BK=32, async dbuf staging (one barrier/BK). Epilogues go
// through the aliased LDS gather buffer -> coalesced uint4 stores.
__global__ __launch_bounds__(256) void gemm_qkv(
    const unsigned short* __restrict__ A,   // x_bf   [4096][1024]
    const unsigned short* __restrict__ Bw,  // wqkv_bf[3072][1024]
    unsigned short* __restrict__ qb, unsigned short* __restrict__ kb,
    unsigned short* __restrict__ vb) {
    const int K = 1024;
    // staging: buf0 { As 4096 | Bs 4096 } buf1 { As | Bs } = 16384 shorts (32 KB)
    // epilogue alias: 4 waves x 64x72 = 18432 shorts (36 KB)
    __shared__ unsigned short smem[18432];
    int tid = threadIdx.x;
    int lane = tid & 63, wave = tid >> 6;
    int wm = (wave & 1) * 64, wn = (wave >> 1) * 64;
    int m0 = blockIdx.y * 128, n0 = blockIdx.x * 128;
    int lm = lane & 15, lq = lane >> 4;

    f32x4 acc[4][4] = {};

    int sdst = tid * 8;  // shorts; lane-contiguous dest
    const unsigned short* gA = A  + (size_t)(m0 + (tid >> 2)) * K + (tid & 3) * 8;
    const unsigned short* gB = Bw + (size_t)(n0 + (tid >> 2)) * K + (tid & 3) * 8;

#define GSTAGE(k0, buf) do {                                          \
        async_cp16(gA + (k0),          smem + (buf) + sdst);          \
        async_cp16(gA + 64 * K + (k0), smem + (buf) + 2048 + sdst);   \
        async_cp16(gB + (k0),          smem + (buf) + 4096 + sdst);   \
        async_cp16(gB + 64 * K + (k0), smem + (buf) + 6144 + sdst);   \
    } while (0)

    GSTAGE(0, 0);
    for (int k0 = 0; k0 < K; k0 += 64) {
        #pragma unroll
        for (int hf = 0; hf < 2; hf++) {
            int base = hf ? 8192 : 0;
            int obuf = hf ? 0 : 8192;
            __syncthreads();  // drains this buffer's loads; other buffer free
            int kn = k0 + 32 + hf * 32;
            if (kn < K) GSTAGE(kn, obuf);
            const unsigned short* As = smem + base;
            const unsigned short* Bs = smem + base + 4096;
            U4S8 af[4], bfx[4];
            #pragma unroll
            for (int i = 0; i < 4; i++) {
                af[i].u  = *(const uint4*)(As + (wm + i * 16 + lm) * 32 + lq * 8);
                bfx[i].u = *(const uint4*)(Bs + (wn + i * 16 + lm) * 32 + lq * 8);
            }
            #pragma unroll
            for (int mi = 0; mi < 4; mi++)
                #pragma unroll
                for (int ni = 0; ni < 4; ni++)
                    acc[mi][ni] = __builtin_amdgcn_mfma_f32_16x16x32_bf16(
                        af[mi].s, bfx[ni].s, acc[mi][ni], 0, 0, 0);
        }
    }
#undef GSTAGE
    __syncthreads();  // staging LDS done before epilogue alias reuse

    // Epilogue. C/D layout: col=lane&15, row=(lane>>4)*4+reg.
    unsigned short* Lw = smem + wave * 4608;  // 64 x 72
    int b = m0 >> 11;
    int s_base = (m0 + wm) & 2047;
    if (n0 < 1024) {
        // ---- v: transpose (store [B,H,HD,S]): Lw[hd][s]
        int h = (n0 + wn) >> 6;
        #pragma unroll
        for (int mi = 0; mi < 4; mi++)
            #pragma unroll
            for (int ni = 0; ni < 4; ni++)
                #pragma unroll
                for (int r = 0; r < 4; r++)
                    Lw[(ni * 16 + lm) * 72 + mi * 16 + lq * 4 + r] =
                        f2bf(acc[mi][ni][r]);
        __builtin_amdgcn_wave_barrier();
        unsigned short* vdst = vb + ((size_t)(b * HH + h) * HDIM) * SS + s_base;
        #pragma unroll
        for (int it = 0; it < 8; it++) {
            int hd = it * 8 + (lane >> 3);
            int so = (lane & 7) * 8;
            uint4 val = *(const uint4*)&Lw[hd * 72 + so];
            *(uint4*)(vdst + (size_t)hd * SS + so) = val;
        }
    } else {
        // ---- q/k: gather (store [B,H,S,HD]): Lw[s][hd], no transpose
        bool isq = n0 < 2048;
        unsigned short* dst = isq ? qb : kb;
        float scale = isq ? 0.18033688f : 1.0f;  // q: fold softmax scale * log2(e)
        int h = ((n0 + wn) >> 6) & 15;
        #pragma unroll
        for (int mi = 0; mi < 4; mi++)
            #pragma unroll
            for (int ni = 0; ni < 4; ni++)
                #pragma unroll
                for (int r = 0; r < 4; r++)
                    Lw[(mi * 16 + lq * 4 + r) * 72 + ni * 16 + lm] =
                        f2bf(acc[mi][ni][r] * scale);
        __builtin_amdgcn_wave_barrier();
        unsigned short* qdst =
            dst + ((size_t)(b * HH + h) * SS + s_base) * HDIM;
        #pragma unroll
        for (int it = 0; it < 8; it++) {
            int srw = it * 8 + (lane >> 3);
            int so = (lane & 7) * 8;
            uint4 val = *(const uint4*)&Lw[srw * 72 + so];
            *(uint4*)(qdst + (size_t)srw * HDIM + so) = val;
        }
    }
}

// ---------------------------------------------------------------- Flash attention
// r12 tech (async dbuf, XOR swizzle, bare v_exp, v_perm pack) + r13: Q-tile 128
// with 2 q-subtiles per wave — each kf/vf LDS read feeds BOTH subtiles' MFMAs,
// halving LDS read bytes per unit work (LDS port was ~53% busy at r12).
// grid x=S/128, y=B*H -> 512 blocks (2/CU, 8 waves/CU). 4 waves x 32 Q-rows.
__global__ __launch_bounds__(256) void attn(
    const unsigned short* __restrict__ qb,  // [B,H,S,HD] pre-scaled (incl. log2e)
    const unsigned short* __restrict__ kb,  // [B,H,S,HD]
    const unsigned short* __restrict__ vb,  // [B,H,HD,S] (transposed)
    unsigned short* __restrict__ ob) {      // [B,S,D]
    int bh = blockIdx.y;
    int q0 = blockIdx.x * 128;
    int tid = threadIdx.x, lane = tid & 63, wave = tid >> 6;
    int lm = lane & 15, lq = lane >> 4;

    // Double buffer: [bufA: Kt 64x64 | Vt 64x64][bufB: same] = 32 KB, no padding.
    __shared__ unsigned short smem[4 * 4096];

    const unsigned short* qg = qb + (size_t)bh * SS * HDIM;
    const unsigned short* kg = kb + (size_t)bh * SS * HDIM;
    const unsigned short* vg = vb + (size_t)bh * HDIM * SS;

    // Q fragments, B-operand of S^T: n=q=lane&15, k=hd=lq*8+j; 2 q-subtiles.
    U4S8 qf[2][2];
    #pragma unroll
    for (int qt = 0; qt < 2; qt++)
        #pragma unroll
        for (int ks = 0; ks < 2; ks++)
            qf[qt][ks].u = *(const uint4*)(
                qg + (size_t)(q0 + wave * 32 + qt * 16 + lm) * HDIM + ks * 32 + lq * 8);

    f32x4 oacc[4][2] = {};        // O^T[hd-tile][q-subtile]
    f32x2 lsum2[2] = {};          // per-lane partial sums per q-subtile

    // ---- loop-invariant swizzled LDS read indices (shorts)
    int lm7 = lm & 7;
    int kidx = lm * 64 + 8 * (lq ^ lm7);          // kf chunk lq (hd 0..31)
    int vidx[4];
    #pragma unroll
    for (int kc = 0; kc < 4; kc++)
        vidx[kc] = lm * 64 + 8 * (((kc << 1) | (lq >> 1)) ^ lm7) + (lq & 1) * 4;

    // ---- staging pointers (async: dest = wave-uniform base + lane*16B)
    int srow = tid >> 3;                  // 0..31
    int scl  = (tid & 7) ^ (srow & 7);    // logical chunk for physical chunk tid&7
    int sdst = tid * 8;                   // shorts
    const unsigned short* kptr = kg + (size_t)srow * HDIM + scl * 8;
    const unsigned short* vptr = vg + (size_t)srow * SS + scl * 8;

    // stage CURRENT pointer tile into buf, then advance pointers one tile.
    #define STAGE(buf)                                                         \
        do {                                                                   \
            async_cp16(kptr,             smem + (buf) + sdst);                 \
            async_cp16(kptr + 32 * HDIM, smem + (buf) + 2048 + sdst);          \
            async_cp16(vptr,             smem + (buf) + 4096 + sdst);          \
            async_cp16(vptr + 32 * SS,   smem + (buf) + 6144 + sdst);          \
            kptr += 64 * HDIM; vptr += 64;                                     \
        } while (0)

    STAGE(0);

    for (int kt = 0; kt < SS / 64; kt += 2) {
        #pragma unroll
        for (int hf = 0; hf < 2; hf++) {
            int base = hf ? 8192 : 0;       // compute buffer
            int obuf = hf ? 0 : 8192;       // stage target (other buffer)
            __syncthreads();  // drains vmcnt: this buffer's loads landed
            STAGE(obuf);  // last iteration over-reads one tile into the
                          // adjacent ws buffer (allocated; data unused)

            // ---- S^T then P^T = 2^(S^T) in regs; kf pair shared by both subtiles
            U2S4 pb[4][2];
            #pragma unroll
            for (int mi = 0; mi < 4; mi++) {
                U4S8 kf0, kf1;
                kf0.u = *(const uint4*)(smem + base + mi * 1024 + kidx);
                kf1.u = *(const uint4*)(smem + base + mi * 1024 + (kidx ^ 32));
                #pragma unroll
                for (int qt = 0; qt < 2; qt++) {
                    f32x4 sa = {};
                    sa = __builtin_amdgcn_mfma_f32_16x16x32_bf16(kf0.s, qf[qt][0].s, sa, 0, 0, 0);
                    sa = __builtin_amdgcn_mfma_f32_16x16x32_bf16(kf1.s, qf[qt][1].s, sa, 0, 0, 0);
                    float p0 = EXP2(sa[0]);
                    float p1 = EXP2(sa[1]);
                    float p2 = EXP2(sa[2]);
                    float p3 = EXP2(sa[3]);
                    f32x2 a01; a01[0] = p0; a01[1] = p1;
                    f32x2 a23; a23[0] = p2; a23[1] = p3;
                    lsum2[qt] += a01;
                    lsum2[qt] += a23;
                    unsigned int b0 = __float_as_uint(p0) + 0x8000u;  // ties-away
                    unsigned int b1 = __float_as_uint(p1) + 0x8000u;
                    unsigned int b2 = __float_as_uint(p2) + 0x8000u;
                    unsigned int b3 = __float_as_uint(p3) + 0x8000u;
                    pb[mi][qt].u.x = __builtin_amdgcn_perm(b1, b0, 0x07060302u);
                    pb[mi][qt].u.y = __builtin_amdgcn_perm(b3, b2, 0x07060302u);
                }
            }

            // ---- O^T += V^T·P^T; vf shared by both subtiles (16x16x16)
            #pragma unroll
            for (int mi2 = 0; mi2 < 4; mi2++) {
                #pragma unroll
                for (int kc = 0; kc < 4; kc++) {
                    U2S4 vf;
                    vf.u = *(const uint2*)(smem + base + 4096 + mi2 * 1024 + vidx[kc]);
                    oacc[mi2][0] = MFMA_PV(vf.s, pb[kc][0].s, oacc[mi2][0]);
                    oacc[mi2][1] = MFMA_PV(vf.s, pb[kc][1].s, oacc[mi2][1]);
                }
            }
        }
    }
    #undef STAGE

    // ---- row sums: lanes lm, lm+16, lm+32, lm+48 hold disjoint k partials
    float inv[2];
    #pragma unroll
    for (int qt = 0; qt < 2; qt++) {
        float s = lsum2[qt][0] + lsum2[qt][1];
        s += __shfl_xor(s, 16);
        s += __shfl_xor(s, 32);
        inv[qt] = 1.f / s;
    }

    // ---- transpose O^T back via smem, store coalesced bf16 [B,S,D]
    __syncthreads();  // all compute done; drains the stray over-read loads
    unsigned short* Ow = smem + wave * (32 * 72);
    #pragma unroll
    for (int mi2 = 0; mi2 < 4; mi2++)
        #pragma unroll
        for (int qt = 0; qt < 2; qt++) {
            U2S4 t;
            #pragma unroll
            for (int r = 0; r < 4; r++)
                t.h[r] = f2bf(oacc[mi2][qt][r] * inv[qt]);
            *(uint2*)&Ow[(qt * 16 + lm) * 72 + mi2 * 16 + lq * 4] = t.u;
        }
    __builtin_amdgcn_wave_barrier();  // Ow wave-local
    int b = bh >> 4, h = bh & 15;
    #pragma unroll
    for (int it = 0; it < 4; it++) {
        int q  = it * 8 + (lane >> 3);
        int off = (lane & 7) * 8;
        uint4 val = *(const uint4*)&Ow[q * 72 + off];
        int srw = q0 + wave * 32 + q;
        *(uint4*)(ob + (size_t)(b * SS + srw) * DD + h * 64 + off) = val;
    }
}

// ---------------------------------------------------------------- Output GEMM
// out[m,e] = sum_d o[m,d] * w_out[e,d] + b_out[e].  M=4096, N=1024, K=1024.
// 128x64 tile -> 512 blocks (2/CU); async dbuf staging, one barrier per BK.
__global__ __launch_bounds__(256) void gemm_out(
    const unsigned short* __restrict__ A,   // o_bf   [4096][1024]
    const unsigned short* __restrict__ Bw,  // wout_bf[1024][1024]
    const float* __restrict__ bias, float* __restrict__ out) {
    const int K = 1024;
    // buf { As 4096 | Bs 2048 } x2 = 12288 shorts (24 KB)
    __shared__ unsigned short smem[12288];
    int tid = threadIdx.x;
    int lane = tid & 63, wave = tid >> 6;
    int wm = (wave & 1) * 64, wn = (wave >> 1) * 32;
    int m0 = blockIdx.y * 128, n0 = blockIdx.x * 64;
    int lm = lane & 15, lq = lane >> 4;

    f32x4 acc[4][2] = {};

    int sdst = tid * 8;
    const unsigned short* gA = A  + (size_t)(m0 + (tid >> 2)) * K + (tid & 3) * 8;
    const unsigned short* gB = Bw + (size_t)(n0 + (tid >> 2)) * K + (tid & 3) * 8;

#define OSTAGE(k0, buf) do {                                          \
        async_cp16(gA + (k0),          smem + (buf) + sdst);          \
        async_cp16(gA + 64 * K + (k0), smem + (buf) + 2048 + sdst);   \
        async_cp16(gB + (k0),          smem + (buf) + 4096 + sdst);   \
    } while (0)

    OSTAGE(0, 0);
    for (int k0 = 0; k0 < K; k0 += 64) {
        #pragma unroll
        for (int hf = 0; hf < 2; hf++) {
            int base = hf ? 6144 : 0;
            int obuf = hf ? 0 : 6144;
            __syncthreads();
            int kn = k0 + 32 + hf * 32;
            if (kn < K) OSTAGE(kn, obuf);
            const unsigned short* As = smem + base;
            const unsigned short* Bs = smem + base + 4096;
            U4S8 af[4], bfx[2];
            #pragma unroll
            for (int i = 0; i < 4; i++)
                af[i].u = *(const uint4*)(As + (wm + i * 16 + lm) * 32 + lq * 8);
            #pragma unroll
            for (int i = 0; i < 2; i++)
                bfx[i].u = *(const uint4*)(Bs + (wn + i * 16 + lm) * 32 + lq * 8);
            #pragma unroll
            for (int mi = 0; mi < 4; mi++)
                #pragma unroll
                for (int ni = 0; ni < 2; ni++)
                    acc[mi][ni] = __builtin_amdgcn_mfma_f32_16x16x32_bf16(
                        af[mi].s, bfx[ni].s, acc[mi][ni], 0, 0, 0);
        }
    }
#undef OSTAGE

    #pragma unroll
    for (int mi = 0; mi < 4; mi++) {
        int gr = m0 + wm + mi * 16 + lq * 4;
        #pragma unroll
        for (int ni = 0; ni < 2; ni++) {
            int gc = n0 + wn + ni * 16 + lm;
            float bv = bias[gc];
            #pragma unroll
            for (int r = 0; r < 4; r++)
                out[(size_t)(gr + r) * DD + gc] = acc[mi][ni][r] + bv;
        }
    }
}

// ---------------------------------------------------------------- launch
extern "C" void kernel_launch(void* const* d_in, const int* in_sizes, int n_in,
                              void* d_out, int out_size, void* d_ws, size_t ws_size,
                              hipStream_t stream) {
    const float* x     = (const float*)d_in[0];
    const float* w_qkv = (const float*)d_in[1];
    const float* w_out = (const float*)d_in[2];
    const float* b_out = (const float*)d_in[3];
    float* out = (float*)d_out;

    unsigned short* ws = (unsigned short*)d_ws;
    const size_t NX = (size_t)BB * SS * DD;        // 4,194,304
    unsigned short* x_bf    = ws;
    unsigned short* wqkv_bf = x_bf + NX;
    unsigned short* wout_bf = wqkv_bf + 3145728;
    unsigned short* q_buf   = wout_bf + 1048576;
    unsigned short* k_buf   = q_buf + NX;
    unsigned short* v_buf   = k_buf + NX;
    unsigned short* o_buf   = v_buf + NX;

    cvt_all<<<4096, 256, 0, stream>>>(x, w_qkv, w_out, x_bf, wqkv_bf, wout_bf);
    gemm_qkv<<<dim3(24, 32), 256, 0, stream>>>(x_bf, wqkv_bf, q_buf, k_buf, v_buf);
    attn<<<dim3(16, 32), 256, 0, stream>>>(q_buf, k_buf, v_buf, o_buf);
    gemm_out<<<dim3(16, 32), 256, 0, stream>>>(o_buf, wout_bf, b_out, out);
}

// Round 14
// 200.718 us; speedup vs baseline: 1.0781x; 1.0211x over previous
//
#include <hip/hip_runtime.h>
#include <cstdint>
#include <cstddef>

// Problem constants
#define BB 2
#define SS 2048
#define DD 1024
#define HH 16
#define HDIM 64
// Attention scale 1/sqrt(64)=0.125 and the exp->exp2 fold log2(e) are
// pre-multiplied into q at the gemm_qkv epilogue: 0.125*1.4426950 = 0.18033688.

typedef short bf16x8 __attribute__((ext_vector_type(8)));
typedef short bf16x4 __attribute__((ext_vector_type(4)));
typedef float f32x4 __attribute__((ext_vector_type(4)));
typedef float f32x2 __attribute__((ext_vector_type(2)));

union U4S8 { uint4 u; bf16x8 s; };
union U2S4 { uint2 u; bf16x4 s; unsigned short h[4]; };

// 16x16x16 bf16 MFMA (K=16). __has_builtin(amdgcn) is FALSE in the host pass
// of HIP's dual compile — guard with __HIP_DEVICE_COMPILE__, dummy for host.
#if defined(__HIP_DEVICE_COMPILE__)
# if __has_builtin(__builtin_amdgcn_mfma_f32_16x16x16bf16_1k)
#  define MFMA_PV(a, b, c) __builtin_amdgcn_mfma_f32_16x16x16bf16_1k((a), (b), (c), 0, 0, 0)
# else
#  define MFMA_PV(a, b, c) __builtin_amdgcn_mfma_f32_16x16x16_bf16((a), (b), (c), 0, 0, 0)
# endif
# if __has_builtin(__builtin_amdgcn_exp2f)
#  define EXP2(x) __builtin_amdgcn_exp2f(x)   // bare v_exp_f32, no libm envelope
# else
#  define EXP2(x) exp2f(x)
# endif
#else
# define MFMA_PV(a, b, c) (c)
# define EXP2(x) exp2f(x)
#endif

__device__ __forceinline__ unsigned short f2bf(float f) {
    union { float f; unsigned int u; } c; c.f = f;
    unsigned int u = c.u;
    unsigned int r = (u + 0x7FFFu + ((u >> 16) & 1u)) >> 16;  // RTNE
    return (unsigned short)r;
}

// async global->LDS, 16B per lane. LDS dest must be wave-uniform base + lane*16.
__device__ __forceinline__ void async_cp16(const void* g, void* l) {
    __builtin_amdgcn_global_load_lds(
        (const __attribute__((address_space(1))) void*)g,
        (__attribute__((address_space(3))) void*)l, 16, 0, 0);
}

// ---------------------------------------------------------------- fp32 -> bf16
// One kernel for all three inputs (x:524288, w_qkv:393216, w_out:131072 uint4s).
__global__ __launch_bounds__(256) void cvt_all(
    const float* __restrict__ x, const float* __restrict__ wq,
    const float* __restrict__ wo,
    unsigned short* __restrict__ xb, unsigned short* __restrict__ wqb,
    unsigned short* __restrict__ wob) {
    int i = blockIdx.x * 256 + threadIdx.x;
    const float* in; unsigned short* out; int j;
    if (i < 524288)       { in = x;  out = xb;  j = i; }
    else if (i < 917504)  { in = wq; out = wqb; j = i - 524288; }
    else                  { in = wo; out = wob; j = i - 917504; }
    float4 a = ((const float4*)in)[2 * j];
    float4 b = ((const float4*)in)[2 * j + 1];
    union { uint4 u; unsigned short h[8]; } o;
    o.h[0] = f2bf(a.x); o.h[1] = f2bf(a.y); o.h[2] = f2bf(a.z); o.h[3] = f2bf(a.w);
    o.h[4] = f2bf(b.x); o.h[5] = f2bf(b.y); o.h[6] = f2bf(b.z); o.h[7] = f2bf(b.w);
    ((uint4*)out)[j] = o.u;
}

// ---------------------------------------------------------------- QKV GEMM
// C[m,e] = sum_d x[m,d] * w_qkv[e,d]  (NT). M=4096, N=3072, K=1024.
// 128x128 tile, BK=32, async dbuf staging (one barrier/BK). Epilogues go
// through the aliased LDS gather buffer -> coalesced uint4 stores.
__global__ __launch_bounds__(256) void gemm_qkv(
    const unsigned short* __restrict__ A,   // x_bf   [4096][1024]
    const unsigned short* __restrict__ Bw,  // wqkv_bf[3072][1024]
    unsigned short* __restrict__ qb, unsigned short* __restrict__ kb,
    unsigned short* __restrict__ vb) {
    const int K = 1024;
    // staging: buf0 { As 4096 | Bs 4096 } buf1 { As | Bs } = 16384 shorts (32 KB)
    // epilogue alias: 4 waves x 64x72 = 18432 shorts (36 KB)
    __shared__ unsigned short smem[18432];
    int tid = threadIdx.x;
    int lane = tid & 63, wave = tid >> 6;
    int wm = (wave & 1) * 64, wn = (wave >> 1) * 64;
    int m0 = blockIdx.y * 128, n0 = blockIdx.x * 128;
    int lm = lane & 15, lq = lane >> 4;

    f32x4 acc[4][4] = {};

    int sdst = tid * 8;  // shorts; lane-contiguous dest
    const unsigned short* gA = A  + (size_t)(m0 + (tid >> 2)) * K + (tid & 3) * 8;
    const unsigned short* gB = Bw + (size_t)(n0 + (tid >> 2)) * K + (tid & 3) * 8;

#define GSTAGE(k0, buf) do {                                          \
        async_cp16(gA + (k0),          smem + (buf) + sdst);          \
        async_cp16(gA + 64 * K + (k0), smem + (buf) + 2048 + sdst);   \
        async_cp16(gB + (k0),          smem + (buf) + 4096 + sdst);   \
        async_cp16(gB + 64 * K + (k0), smem + (buf) + 6144 + sdst);   \
    } while (0)

    GSTAGE(0, 0);
    for (int k0 = 0; k0 < K; k0 += 64) {
        #pragma unroll
        for (int hf = 0; hf < 2; hf++) {
            int base = hf ? 8192 : 0;
            int obuf = hf ? 0 : 8192;
            __syncthreads();  // drains this buffer's loads; other buffer free
            int kn = k0 + 32 + hf * 32;
            if (kn < K) GSTAGE(kn, obuf);
            const unsigned short* As = smem + base;
            const unsigned short* Bs = smem + base + 4096;
            U4S8 af[4], bfx[4];
            #pragma unroll
            for (int i = 0; i < 4; i++) {
                af[i].u  = *(const uint4*)(As + (wm + i * 16 + lm) * 32 + lq * 8);
                bfx[i].u = *(const uint4*)(Bs + (wn + i * 16 + lm) * 32 + lq * 8);
            }
            #pragma unroll
            for (int mi = 0; mi < 4; mi++)
                #pragma unroll
                for (int ni = 0; ni < 4; ni++)
                    acc[mi][ni] = __builtin_amdgcn_mfma_f32_16x16x32_bf16(
                        af[mi].s, bfx[ni].s, acc[mi][ni], 0, 0, 0);
        }
    }
#undef GSTAGE
    __syncthreads();  // staging LDS done before epilogue alias reuse

    // Epilogue. C/D layout: col=lane&15, row=(lane>>4)*4+reg.
    unsigned short* Lw = smem + wave * 4608;  // 64 x 72
    int b = m0 >> 11;
    int s_base = (m0 + wm) & 2047;
    if (n0 < 1024) {
        // ---- v: transpose (store [B,H,HD,S]): Lw[hd][s]
        int h = (n0 + wn) >> 6;
        #pragma unroll
        for (int mi = 0; mi < 4; mi++)
            #pragma unroll
            for (int ni = 0; ni < 4; ni++)
                #pragma unroll
                for (int r = 0; r < 4; r++)
                    Lw[(ni * 16 + lm) * 72 + mi * 16 + lq * 4 + r] =
                        f2bf(acc[mi][ni][r]);
        __builtin_amdgcn_wave_barrier();
        unsigned short* vdst = vb + ((size_t)(b * HH + h) * HDIM) * SS + s_base;
        #pragma unroll
        for (int it = 0; it < 8; it++) {
            int hd = it * 8 + (lane >> 3);
            int so = (lane & 7) * 8;
            uint4 val = *(const uint4*)&Lw[hd * 72 + so];
            *(uint4*)(vdst + (size_t)hd * SS + so) = val;
        }
    } else {
        // ---- q/k: gather (store [B,H,S,HD]): Lw[s][hd], no transpose
        bool isq = n0 < 2048;
        unsigned short* dst = isq ? qb : kb;
        float scale = isq ? 0.18033688f : 1.0f;  // q: fold softmax scale * log2(e)
        int h = ((n0 + wn) >> 6) & 15;
        #pragma unroll
        for (int mi = 0; mi < 4; mi++)
            #pragma unroll
            for (int ni = 0; ni < 4; ni++)
                #pragma unroll
                for (int r = 0; r < 4; r++)
                    Lw[(mi * 16 + lq * 4 + r) * 72 + ni * 16 + lm] =
                        f2bf(acc[mi][ni][r] * scale);
        __builtin_amdgcn_wave_barrier();
        unsigned short* qdst =
            dst + ((size_t)(b * HH + h) * SS + s_base) * HDIM;
        #pragma unroll
        for (int it = 0; it < 8; it++) {
            int srw = it * 8 + (lane >> 3);
            int so = (lane & 7) * 8;
            uint4 val = *(const uint4*)&Lw[srw * 72 + so];
            *(uint4*)(qdst + (size_t)srw * HDIM + so) = val;
        }
    }
}

// ---------------------------------------------------------------- Flash attention
// r13 per-wave economics at 2x the waves: 512-thread blocks, 8 waves in 2
// k-groups. Group g computes k-positions g*64..+63 of each 128-wide K-tile;
// each wave keeps the r13 tile shape (4 mi x 2 q-subtiles, kf/vf reused).
// LDS: pair-dbuf of {KA,KB,VA,VB} 64x64 tiles = 64 KB -> 2 blocks/CU
// -> 16 waves/CU (r13 was latency-bound at 8). Epilogue: group 1 publishes
// raw fp32 O^T + row sums via LDS (SoA), group 0 combines and writes.
__global__ __launch_bounds__(512) void attn(
    const unsigned short* __restrict__ qb,  // [B,H,S,HD] pre-scaled (incl. log2e)
    const unsigned short* __restrict__ kb,  // [B,H,S,HD]
    const unsigned short* __restrict__ vb,  // [B,H,HD,S] (transposed)
    unsigned short* __restrict__ ob) {      // [B,S,D]
    int bh = blockIdx.y;
    int q0 = blockIdx.x * 128;
    int tid = threadIdx.x, lane = tid & 63, wave = tid >> 6;
    int grp = wave >> 2;      // k-half
    int w4  = wave & 3;       // wave-in-group: owns q rows w4*32..+31
    int lm = lane & 15, lq = lane >> 4;

    // [pair 2][KA|KB|VA|VB, 4096 shorts each] = 32768 shorts = 64 KB
    __shared__ unsigned short smem[32768];
    float* smf = (float*)smem;

    const unsigned short* qg = qb + (size_t)bh * SS * HDIM;
    const unsigned short* kg = kb + (size_t)bh * SS * HDIM;
    const unsigned short* vg = vb + (size_t)bh * HDIM * SS;

    // Q fragments (both groups load the same q rows for their k-half)
    U4S8 qf[2][2];
    #pragma unroll
    for (int qt = 0; qt < 2; qt++)
        #pragma unroll
        for (int ks = 0; ks < 2; ks++)
            qf[qt][ks].u = *(const uint4*)(
                qg + (size_t)(q0 + w4 * 32 + qt * 16 + lm) * HDIM + ks * 32 + lq * 8);

    f32x4 oacc[4][2] = {};        // O^T[hd-tile][q-subtile] (this group's k-half)
    f32x2 lsum2[2] = {};

    // ---- loop-invariant swizzled LDS read indices within a 64x64 tile (shorts)
    int lm7 = lm & 7;
    int kidx = lm * 64 + 8 * (lq ^ lm7);
    int vidx[4];
    #pragma unroll
    for (int kc = 0; kc < 4; kc++)
        vidx[kc] = lm * 64 + 8 * (((kc << 1) | (lq >> 1)) ^ lm7) + (lq & 1) * 4;

    // ---- staging: 512 threads x 4 async-16B = one 128-wide K-tile (K + V)
    int srow = tid >> 3;               // 0..63
    int lch  = (tid & 7) ^ (srow & 7); // logical chunk for physical chunk tid&7
    int sdst = tid * 8;                // 0..4095 shorts within each region
    const unsigned short* kpA = kg + (size_t)srow * HDIM + lch * 8;  // rows 0-63
    const unsigned short* kpB = kpA + 64 * HDIM;                     // rows 64-127
    const unsigned short* vpA = vg + (size_t)srow * SS + lch * 8;    // kpos 0-63
    const unsigned short* vpB = vpA + 64;                            // kpos 64-127

    #define STAGE(pbase)                                                       \
        do {                                                                   \
            async_cp16(kpA, smem + (pbase) + sdst);                            \
            async_cp16(kpB, smem + (pbase) + 4096 + sdst);                     \
            async_cp16(vpA, smem + (pbase) + 8192 + sdst);                     \
            async_cp16(vpB, smem + (pbase) + 12288 + sdst);                    \
            kpA += 128 * HDIM; kpB += 128 * HDIM; vpA += 128; vpB += 128;      \
        } while (0)

    STAGE(0);

    for (int kt = 0; kt < SS / 128; kt += 2) {
        #pragma unroll
        for (int hf = 0; hf < 2; hf++) {
            int cbase = hf ? 16384 : 0;      // compute pair
            int obase = hf ? 0 : 16384;      // stage target pair
            __syncthreads();  // drains vmcnt: compute pair's loads landed
            STAGE(obase);  // last iter over-reads one tile into adjacent ws buf

            int kbase = cbase + grp * 4096;
            int vbase = cbase + 8192 + grp * 4096;

            // ---- S^T then P^T = 2^(S^T) in regs; kf shared by both q-subtiles
            U2S4 pb[4][2];
            #pragma unroll
            for (int mi = 0; mi < 4; mi++) {
                U4S8 kf0, kf1;
                kf0.u = *(const uint4*)(smem + kbase + mi * 1024 + kidx);
                kf1.u = *(const uint4*)(smem + kbase + mi * 1024 + (kidx ^ 32));
                #pragma unroll
                for (int qt = 0; qt < 2; qt++) {
                    f32x4 sa = {};
                    sa = __builtin_amdgcn_mfma_f32_16x16x32_bf16(kf0.s, qf[qt][0].s, sa, 0, 0, 0);
                    sa = __builtin_amdgcn_mfma_f32_16x16x32_bf16(kf1.s, qf[qt][1].s, sa, 0, 0, 0);
                    float p0 = EXP2(sa[0]);
                    float p1 = EXP2(sa[1]);
                    float p2 = EXP2(sa[2]);
                    float p3 = EXP2(sa[3]);
                    f32x2 a01; a01[0] = p0; a01[1] = p1;
                    f32x2 a23; a23[0] = p2; a23[1] = p3;
                    lsum2[qt] += a01;
                    lsum2[qt] += a23;
                    unsigned int b0 = __float_as_uint(p0) + 0x8000u;  // ties-away
                    unsigned int b1 = __float_as_uint(p1) + 0x8000u;
                    unsigned int b2 = __float_as_uint(p2) + 0x8000u;
                    unsigned int b3 = __float_as_uint(p3) + 0x8000u;
                    pb[mi][qt].u.x = __builtin_amdgcn_perm(b1, b0, 0x07060302u);
                    pb[mi][qt].u.y = __builtin_amdgcn_perm(b3, b2, 0x07060302u);
                }
            }

            // ---- O^T += V^T·P^T; vf shared by both subtiles (16x16x16)
            #pragma unroll
            for (int mi2 = 0; mi2 < 4; mi2++) {
                #pragma unroll
                for (int kc = 0; kc < 4; kc++) {
                    U2S4 vf;
                    vf.u = *(const uint2*)(smem + vbase + mi2 * 1024 + vidx[kc]);
                    oacc[mi2][0] = MFMA_PV(vf.s, pb[kc][0].s, oacc[mi2][0]);
                    oacc[mi2][1] = MFMA_PV(vf.s, pb[kc][1].s, oacc[mi2][1]);
                }
            }
        }
    }
    #undef STAGE

    // ---- per-group row sums (lanes lm,+16,+32,+48 hold disjoint k partials)
    float gsum[2];
    #pragma unroll
    for (int qt = 0; qt < 2; qt++) {
        float s = lsum2[qt][0] + lsum2[qt][1];
        s += __shfl_xor(s, 16);
        s += __shfl_xor(s, 32);
        gsum[qt] = s;
    }

    __syncthreads();  // all compute done; drains stray over-read loads

    // ---- group 1 publishes raw O^T + sums (SoA: word j at j*64+lane, no conflicts)
    if (grp == 1) {
        float* pub = smf + w4 * 2048;
        #pragma unroll
        for (int mi2 = 0; mi2 < 4; mi2++)
            #pragma unroll
            for (int qt = 0; qt < 2; qt++)
                #pragma unroll
                for (int r = 0; r < 4; r++)
                    pub[(mi2 * 8 + qt * 4 + r) * 64 + lane] = oacc[mi2][qt][r];
        if (lq == 0) {
            smf[8192 + w4 * 32 + lm]      = gsum[0];
            smf[8192 + w4 * 32 + 16 + lm] = gsum[1];
        }
    }
    __syncthreads();

    // ---- group 0 combines, normalizes, writes output
    if (grp == 0) {
        float* pub = smf + w4 * 2048;
        #pragma unroll
        for (int mi2 = 0; mi2 < 4; mi2++)
            #pragma unroll
            for (int qt = 0; qt < 2; qt++)
                #pragma unroll
                for (int r = 0; r < 4; r++)
                    oacc[mi2][qt][r] += pub[(mi2 * 8 + qt * 4 + r) * 64 + lane];
        float inv[2];
        inv[0] = 1.f / (gsum[0] + smf[8192 + w4 * 32 + lm]);
        inv[1] = 1.f / (gsum[1] + smf[8192 + w4 * 32 + 16 + lm]);

        // transpose O^T back via smem (region disjoint from publish), coalesced store
        unsigned short* Ow = smem + 17024 + w4 * 2304;  // 32 x 72
        #pragma unroll
        for (int mi2 = 0; mi2 < 4; mi2++)
            #pragma unroll
            for (int qt = 0; qt < 2; qt++) {
                U2S4 t;
                #pragma unroll
                for (int r = 0; r < 4; r++)
                    t.h[r] = f2bf(oacc[mi2][qt][r] * inv[qt]);
                *(uint2*)&Ow[(qt * 16 + lm) * 72 + mi2 * 16 + lq * 4] = t.u;
            }
        __builtin_amdgcn_wave_barrier();  // Ow wave-local
        int b = bh >> 4, h = bh & 15;
        #pragma unroll
        for (int it = 0; it < 4; it++) {
            int q  = it * 8 + (lane >> 3);
            int off = (lane & 7) * 8;
            uint4 val = *(const uint4*)&Ow[q * 72 + off];
            int srw = q0 + w4 * 32 + q;
            *(uint4*)(ob + (size_t)(b * SS + srw) * DD + h * 64 + off) = val;
        }
    }
}

// ---------------------------------------------------------------- Output GEMM
// out[m,e] = sum_d o[m,d] * w_out[e,d] + b_out[e].  M=4096, N=1024, K=1024.
// 128x64 tile -> 512 blocks (2/CU); async dbuf staging, one barrier per BK.
__global__ __launch_bounds__(256) void gemm_out(
    const unsigned short* __restrict__ A,   // o_bf   [4096][1024]
    const unsigned short* __restrict__ Bw,  // wout_bf[1024][1024]
    const float* __restrict__ bias, float* __restrict__ out) {
    const int K = 1024;
    // buf { As 4096 | Bs 2048 } x2 = 12288 shorts (24 KB)
    __shared__ unsigned short smem[12288];
    int tid = threadIdx.x;
    int lane = tid & 63, wave = tid >> 6;
    int wm = (wave & 1) * 64, wn = (wave >> 1) * 32;
    int m0 = blockIdx.y * 128, n0 = blockIdx.x * 64;
    int lm = lane & 15, lq = lane >> 4;

    f32x4 acc[4][2] = {};

    int sdst = tid * 8;
    const unsigned short* gA = A  + (size_t)(m0 + (tid >> 2)) * K + (tid & 3) * 8;
    const unsigned short* gB = Bw + (size_t)(n0 + (tid >> 2)) * K + (tid & 3) * 8;

#define OSTAGE(k0, buf) do {                                          \
        async_cp16(gA + (k0),          smem + (buf) + sdst);          \
        async_cp16(gA + 64 * K + (k0), smem + (buf) + 2048 + sdst);   \
        async_cp16(gB + (k0),          smem + (buf) + 4096 + sdst);   \
    } while (0)

    OSTAGE(0, 0);
    for (int k0 = 0; k0 < K; k0 += 64) {
        #pragma unroll
        for (int hf = 0; hf < 2; hf++) {
            int base = hf ? 6144 : 0;
            int obuf = hf ? 0 : 6144;
            __syncthreads();
            int kn = k0 + 32 + hf * 32;
            if (kn < K) OSTAGE(kn, obuf);
            const unsigned short* As = smem + base;
            const unsigned short* Bs = smem + base + 4096;
            U4S8 af[4], bfx[2];
            #pragma unroll
            for (int i = 0; i < 4; i++)
                af[i].u = *(const uint4*)(As + (wm + i * 16 + lm) * 32 + lq * 8);
            #pragma unroll
            for (int i = 0; i < 2; i++)
                bfx[i].u = *(const uint4*)(Bs + (wn + i * 16 + lm) * 32 + lq * 8);
            #pragma unroll
            for (int mi = 0; mi < 4; mi++)
                #pragma unroll
                for (int ni = 0; ni < 2; ni++)
                    acc[mi][ni] = __builtin_amdgcn_mfma_f32_16x16x32_bf16(
                        af[mi].s, bfx[ni].s, acc[mi][ni], 0, 0, 0);
        }
    }
#undef OSTAGE

    #pragma unroll
    for (int mi = 0; mi < 4; mi++) {
        int gr = m0 + wm + mi * 16 + lq * 4;
        #pragma unroll
        for (int ni = 0; ni < 2; ni++) {
            int gc = n0 + wn + ni * 16 + lm;
            float bv = bias[gc];
            #pragma unroll
            for (int r = 0; r < 4; r++)
                out[(size_t)(gr + r) * DD + gc] = acc[mi][ni][r] + bv;
        }
    }
}

// ---------------------------------------------------------------- launch
extern "C" void kernel_launch(void* const* d_in, const int* in_sizes, int n_in,
                              void* d_out, int out_size, void* d_ws, size_t ws_size,
                              hipStream_t stream) {
    const float* x     = (const float*)d_in[0];
    const float* w_qkv = (const float*)d_in[1];
    const float* w_out = (const float*)d_in[2];
    const float* b_out = (const float*)d_in[3];
    float* out = (float*)d_out;

    unsigned short* ws = (unsigned short*)d_ws;
    const size_t NX = (size_t)BB * SS * DD;        // 4,194,304
    unsigned short* x_bf    = ws;
    unsigned short* wqkv_bf = x_bf + NX;
    unsigned short* wout_bf = wqkv_bf + 3145728;
    unsigned short* q_buf   = wout_bf + 1048576;
    unsigned short* k_buf   = q_buf + NX;
    unsigned short* v_buf   = k_buf + NX;
    unsigned short* o_buf   = v_buf + NX;

    cvt_all<<<4096, 256, 0, stream>>>(x, w_qkv, w_out, x_bf, wqkv_bf, wout_bf);
    gemm_qkv<<<dim3(24, 32), 256, 0, stream>>>(x_bf, wqkv_bf, q_buf, k_buf, v_buf);
    attn<<<dim3(16, 32), 512, 0, stream>>>(q_buf, k_buf, v_buf, o_buf);
    gemm_out<<<dim3(16, 32), 256, 0, stream>>>(o_buf, wout_bf, b_out, out);
}

// Round 15
// 194.748 us; speedup vs baseline: 1.1112x; 1.0307x over previous
//
#include <hip/hip_runtime.h>
#include <cstdint>
#include <cstddef>

// Problem constants
#define BB 2
#define SS 2048
#define DD 1024
#define HH 16
#define HDIM 64
// Attention scale 1/sqrt(64)=0.125 and the exp->exp2 fold log2(e) are
// pre-multiplied into q at the gemm_qkv epilogue: 0.125*1.4426950 = 0.18033688.

typedef short bf16x8 __attribute__((ext_vector_type(8)));
typedef short bf16x4 __attribute__((ext_vector_type(4)));
typedef float f32x4 __attribute__((ext_vector_type(4)));
typedef float f32x2 __attribute__((ext_vector_type(2)));

union U4S8 { uint4 u; bf16x8 s; };
union U2S4 { uint2 u; bf16x4 s; unsigned short h[4]; };

#if defined(__HIP_DEVICE_COMPILE__)
# if __has_builtin(__builtin_amdgcn_exp2f)
#  define EXP2(x) __builtin_amdgcn_exp2f(x)   // bare v_exp_f32, no libm envelope
# else
#  define EXP2(x) exp2f(x)
# endif
#else
# define EXP2(x) exp2f(x)
#endif

__device__ __forceinline__ unsigned short f2bf(float f) {
    union { float f; unsigned int u; } c; c.f = f;
    unsigned int u = c.u;
    unsigned int r = (u + 0x7FFFu + ((u >> 16) & 1u)) >> 16;  // RTNE
    return (unsigned short)r;
}

// async global->LDS, 16B per lane. LDS dest must be wave-uniform base + lane*16.
__device__ __forceinline__ void async_cp16(const void* g, void* l) {
    __builtin_amdgcn_global_load_lds(
        (const __attribute__((address_space(1))) void*)g,
        (__attribute__((address_space(3))) void*)l, 16, 0, 0);
}

// ---------------------------------------------------------------- fp32 -> bf16
// One kernel for all three inputs (x:524288, w_qkv:393216, w_out:131072 uint4s).
__global__ __launch_bounds__(256) void cvt_all(
    const float* __restrict__ x, const float* __restrict__ wq,
    const float* __restrict__ wo,
    unsigned short* __restrict__ xb, unsigned short* __restrict__ wqb,
    unsigned short* __restrict__ wob) {
    int i = blockIdx.x * 256 + threadIdx.x;
    const float* in; unsigned short* out; int j;
    if (i < 524288)       { in = x;  out = xb;  j = i; }
    else if (i < 917504)  { in = wq; out = wqb; j = i - 524288; }
    else                  { in = wo; out = wob; j = i - 917504; }
    float4 a = ((const float4*)in)[2 * j];
    float4 b = ((const float4*)in)[2 * j + 1];
    union { uint4 u; unsigned short h[8]; } o;
    o.h[0] = f2bf(a.x); o.h[1] = f2bf(a.y); o.h[2] = f2bf(a.z); o.h[3] = f2bf(a.w);
    o.h[4] = f2bf(b.x); o.h[5] = f2bf(b.y); o.h[6] = f2bf(b.z); o.h[7] = f2bf(b.w);
    ((uint4*)out)[j] = o.u;
}

// ---------------------------------------------------------------- QKV GEMM
// C[m,e] = sum_d x[m,d] * w_qkv[e,d]  (NT). M=4096, N=3072, K=1024.
// 128x128 tile, BK=32, async dbuf staging (one barrier/BK). Epilogues go
// through the aliased LDS gather buffer -> coalesced uint4 stores.
__global__ __launch_bounds__(256) void gemm_qkv(
    const unsigned short* __restrict__ A,   // x_bf   [4096][1024]
    const unsigned short* __restrict__ Bw,  // wqkv_bf[3072][1024]
    unsigned short* __restrict__ qb, unsigned short* __restrict__ kb,
    unsigned short* __restrict__ vb) {
    const int K = 1024;
    __shared__ unsigned short smem[18432];
    int tid = threadIdx.x;
    int lane = tid & 63, wave = tid >> 6;
    int wm = (wave & 1) * 64, wn = (wave >> 1) * 64;
    int m0 = blockIdx.y * 128, n0 = blockIdx.x * 128;
    int lm = lane & 15, lq = lane >> 4;

    f32x4 acc[4][4] = {};

    int sdst = tid * 8;  // shorts; lane-contiguous dest
    const unsigned short* gA = A  + (size_t)(m0 + (tid >> 2)) * K + (tid & 3) * 8;
    const unsigned short* gB = Bw + (size_t)(n0 + (tid >> 2)) * K + (tid & 3) * 8;

#define GSTAGE(k0, buf) do {                                          \
        async_cp16(gA + (k0),          smem + (buf) + sdst);          \
        async_cp16(gA + 64 * K + (k0), smem + (buf) + 2048 + sdst);   \
        async_cp16(gB + (k0),          smem + (buf) + 4096 + sdst);   \
        async_cp16(gB + 64 * K + (k0), smem + (buf) + 6144 + sdst);   \
    } while (0)

    GSTAGE(0, 0);
    for (int k0 = 0; k0 < K; k0 += 64) {
        #pragma unroll
        for (int hf = 0; hf < 2; hf++) {
            int base = hf ? 8192 : 0;
            int obuf = hf ? 0 : 8192;
            __syncthreads();  // drains this buffer's loads; other buffer free
            int kn = k0 + 32 + hf * 32;
            if (kn < K) GSTAGE(kn, obuf);
            const unsigned short* As = smem + base;
            const unsigned short* Bs = smem + base + 4096;
            U4S8 af[4], bfx[4];
            #pragma unroll
            for (int i = 0; i < 4; i++) {
                af[i].u  = *(const uint4*)(As + (wm + i * 16 + lm) * 32 + lq * 8);
                bfx[i].u = *(const uint4*)(Bs + (wn + i * 16 + lm) * 32 + lq * 8);
            }
            #pragma unroll
            for (int mi = 0; mi < 4; mi++)
                #pragma unroll
                for (int ni = 0; ni < 4; ni++)
                    acc[mi][ni] = __builtin_amdgcn_mfma_f32_16x16x32_bf16(
                        af[mi].s, bfx[ni].s, acc[mi][ni], 0, 0, 0);
        }
    }
#undef GSTAGE
    __syncthreads();  // staging LDS done before epilogue alias reuse

    // Epilogue. C/D layout: col=lane&15, row=(lane>>4)*4+reg.
    unsigned short* Lw = smem + wave * 4608;  // 64 x 72
    int b = m0 >> 11;
    int s_base = (m0 + wm) & 2047;
    if (n0 < 1024) {
        // ---- v: transpose (store [B,H,HD,S]): Lw[hd][s]
        int h = (n0 + wn) >> 6;
        #pragma unroll
        for (int mi = 0; mi < 4; mi++)
            #pragma unroll
            for (int ni = 0; ni < 4; ni++)
                #pragma unroll
                for (int r = 0; r < 4; r++)
                    Lw[(ni * 16 + lm) * 72 + mi * 16 + lq * 4 + r] =
                        f2bf(acc[mi][ni][r]);
        __builtin_amdgcn_wave_barrier();
        unsigned short* vdst = vb + ((size_t)(b * HH + h) * HDIM) * SS + s_base;
        #pragma unroll
        for (int it = 0; it < 8; it++) {
            int hd = it * 8 + (lane >> 3);
            int so = (lane & 7) * 8;
            uint4 val = *(const uint4*)&Lw[hd * 72 + so];
            *(uint4*)(vdst + (size_t)hd * SS + so) = val;
        }
    } else {
        // ---- q/k: gather (store [B,H,S,HD]): Lw[s][hd], no transpose
        bool isq = n0 < 2048;
        unsigned short* dst = isq ? qb : kb;
        float scale = isq ? 0.18033688f : 1.0f;  // q: fold softmax scale * log2(e)
        int h = ((n0 + wn) >> 6) & 15;
        #pragma unroll
        for (int mi = 0; mi < 4; mi++)
            #pragma unroll
            for (int ni = 0; ni < 4; ni++)
                #pragma unroll
                for (int r = 0; r < 4; r++)
                    Lw[(mi * 16 + lq * 4 + r) * 72 + ni * 16 + lm] =
                        f2bf(acc[mi][ni][r] * scale);
        __builtin_amdgcn_wave_barrier();
        unsigned short* qdst =
            dst + ((size_t)(b * HH + h) * SS + s_base) * HDIM;
        #pragma unroll
        for (int it = 0; it < 8; it++) {
            int srw = it * 8 + (lane >> 3);
            int so = (lane & 7) * 8;
            uint4 val = *(const uint4*)&Lw[srw * 72 + so];
            *(uint4*)(qdst + (size_t)srw * HDIM + so) = val;
        }
    }
}

// ---------------------------------------------------------------- Flash attention
// r14 structure (512-thr k-split blocks, async dbuf, XOR swizzle) + r15:
// PV upgraded to K=32 MFMA via KAPPA-PERMUTED K staging. K rows are stored in
// LDS slots such that the S^T C-layout rows a lane holds (4lq..4lq+3 per
// 16-tile) ARE k = 8lq+j (tile even) and 8lq+4+j (tile odd): a tile-pair's
// exp'd P^T concatenates in-register into a 16x16x32 B-operand (k=lq*8+j).
// V stays identity-ordered; PV A-side reads true-k b128 runs from Vt
// (also halves vf DS instruction count). Scores/sums are k-order-agnostic.
__global__ __launch_bounds__(512) void attn(
    const unsigned short* __restrict__ qb,  // [B,H,S,HD] pre-scaled (incl. log2e)
    const unsigned short* __restrict__ kb,  // [B,H,S,HD]
    const unsigned short* __restrict__ vb,  // [B,H,HD,S] (transposed)
    unsigned short* __restrict__ ob) {      // [B,S,D]
    int bh = blockIdx.y;
    int q0 = blockIdx.x * 128;
    int tid = threadIdx.x, lane = tid & 63, wave = tid >> 6;
    int grp = wave >> 2;      // k-half
    int w4  = wave & 3;       // wave-in-group: owns q rows w4*32..+31
    int lm = lane & 15, lq = lane >> 4;

    // [pair 2][KA|KB|VA|VB, 4096 shorts each] = 32768 shorts = 64 KB
    __shared__ unsigned short smem[32768];
    float* smf = (float*)smem;

    const unsigned short* qg = qb + (size_t)bh * SS * HDIM;
    const unsigned short* kg = kb + (size_t)bh * SS * HDIM;
    const unsigned short* vg = vb + (size_t)bh * HDIM * SS;

    // Q fragments (both groups load the same q rows for their k-half)
    U4S8 qf[2][2];
    #pragma unroll
    for (int qt = 0; qt < 2; qt++)
        #pragma unroll
        for (int ks = 0; ks < 2; ks++)
            qf[qt][ks].u = *(const uint4*)(
                qg + (size_t)(q0 + w4 * 32 + qt * 16 + lm) * HDIM + ks * 32 + lq * 8);

    f32x4 oacc[4][2] = {};        // O^T[hd-tile][q-subtile] (this group's k-half)
    f32x2 lsum2[2] = {};

    // ---- loop-invariant swizzled LDS read indices within a 64x64 tile (shorts)
    int lm7 = lm & 7;
    int kidx = lm * 64 + 8 * (lq ^ lm7);          // kf b128 (slot rows)
    int vidx[2];                                  // vf b128: kpos kb*32+lq*8 (true k)
    #pragma unroll
    for (int kblk = 0; kblk < 2; kblk++)
        vidx[kblk] = lm * 64 + 8 * (((kblk << 2) | lq) ^ lm7);

    // ---- staging: 512 threads x 4 async-16B = one 128-wide K-tile (K + V)
    // K source row is KAPPA-permuted: LDS slot s holds k-row kappa(s), where
    // kappa(s) = 32*(s>>5) + 8*((s>>2)&3) + 4*((s>>4)&1) + (s&3)  (s in 0..63)
    int sr  = tid >> 3;                // LDS slot row 0..63
    int s5  = sr & 31;
    int kap = (sr & 32) + (((s5 >> 2) & 3) << 3) + (((s5 >> 4) & 1) << 2) + (s5 & 3);
    int lch = (tid & 7) ^ (sr & 7);    // chunk swizzle keyed by SLOT row
    int sdst = tid * 8;                // shorts within each 4096-short region
    const unsigned short* kpA = kg + (size_t)kap * HDIM + lch * 8;   // slots 0-63
    const unsigned short* kpB = kpA + 64 * HDIM;                     // slots 64-127
    const unsigned short* vpA = vg + (size_t)sr * SS + lch * 8;      // kpos 0-63
    const unsigned short* vpB = vpA + 64;                            // kpos 64-127

    #define STAGE(pbase)                                                       \
        do {                                                                   \
            async_cp16(kpA, smem + (pbase) + sdst);                            \
            async_cp16(kpB, smem + (pbase) + 4096 + sdst);                     \
            async_cp16(vpA, smem + (pbase) + 8192 + sdst);                     \
            async_cp16(vpB, smem + (pbase) + 12288 + sdst);                    \
            kpA += 128 * HDIM; kpB += 128 * HDIM; vpA += 128; vpB += 128;      \
        } while (0)

    STAGE(0);

    for (int kt = 0; kt < SS / 128; kt += 2) {
        #pragma unroll
        for (int hf = 0; hf < 2; hf++) {
            int cbase = hf ? 16384 : 0;      // compute pair
            int obase = hf ? 0 : 16384;      // stage target pair
            __syncthreads();  // drains vmcnt: compute pair's loads landed
            STAGE(obase);  // last iter over-reads one tile into adjacent ws buf

            int kbase = cbase + grp * 4096;
            int vbase = cbase + 8192 + grp * 4096;

            // ---- S^T then P^T = 2^(S^T): tile-pair halves fill the K=32
            //      B-operand directly (kappa staging makes r-index == j)
            U4S8 pb8[2][2];   // [kblk][qt]: full 16x16x32 B-operand fragments
            #pragma unroll
            for (int mi = 0; mi < 4; mi++) {
                U4S8 kf0, kf1;
                kf0.u = *(const uint4*)(smem + kbase + mi * 1024 + kidx);
                kf1.u = *(const uint4*)(smem + kbase + mi * 1024 + (kidx ^ 32));
                #pragma unroll
                for (int qt = 0; qt < 2; qt++) {
                    f32x4 sa = {};
                    sa = __builtin_amdgcn_mfma_f32_16x16x32_bf16(kf0.s, qf[qt][0].s, sa, 0, 0, 0);
                    sa = __builtin_amdgcn_mfma_f32_16x16x32_bf16(kf1.s, qf[qt][1].s, sa, 0, 0, 0);
                    float p0 = EXP2(sa[0]);
                    float p1 = EXP2(sa[1]);
                    float p2 = EXP2(sa[2]);
                    float p3 = EXP2(sa[3]);
                    f32x2 a01; a01[0] = p0; a01[1] = p1;
                    f32x2 a23; a23[0] = p2; a23[1] = p3;
                    lsum2[qt] += a01;
                    lsum2[qt] += a23;
                    unsigned int b0 = __float_as_uint(p0) + 0x8000u;  // ties-away
                    unsigned int b1 = __float_as_uint(p1) + 0x8000u;
                    unsigned int b2 = __float_as_uint(p2) + 0x8000u;
                    unsigned int b3 = __float_as_uint(p3) + 0x8000u;
                    unsigned int lo = __builtin_amdgcn_perm(b1, b0, 0x07060302u);
                    unsigned int hi = __builtin_amdgcn_perm(b3, b2, 0x07060302u);
                    if ((mi & 1) == 0) { pb8[mi >> 1][qt].u.x = lo; pb8[mi >> 1][qt].u.y = hi; }
                    else               { pb8[mi >> 1][qt].u.z = lo; pb8[mi >> 1][qt].u.w = hi; }
                }
            }

            // ---- O^T += V^T·P^T at K=32 (half the r14 PV instruction count)
            #pragma unroll
            for (int mi2 = 0; mi2 < 4; mi2++) {
                #pragma unroll
                for (int kblk = 0; kblk < 2; kblk++) {
                    U4S8 vf;
                    vf.u = *(const uint4*)(smem + vbase + mi2 * 1024 + vidx[kblk]);
                    oacc[mi2][0] = __builtin_amdgcn_mfma_f32_16x16x32_bf16(
                        vf.s, pb8[kblk][0].s, oacc[mi2][0], 0, 0, 0);
                    oacc[mi2][1] = __builtin_amdgcn_mfma_f32_16x16x32_bf16(
                        vf.s, pb8[kblk][1].s, oacc[mi2][1], 0, 0, 0);
                }
            }
        }
    }
    #undef STAGE

    // ---- per-group row sums (lanes lm,+16,+32,+48 hold disjoint k partials)
    float gsum[2];
    #pragma unroll
    for (int qt = 0; qt < 2; qt++) {
        float s = lsum2[qt][0] + lsum2[qt][1];
        s += __shfl_xor(s, 16);
        s += __shfl_xor(s, 32);
        gsum[qt] = s;
    }

    __syncthreads();  // all compute done; drains stray over-read loads

    // ---- group 1 publishes raw O^T + sums (SoA: word j at j*64+lane, no conflicts)
    if (grp == 1) {
        float* pub = smf + w4 * 2048;
        #pragma unroll
        for (int mi2 = 0; mi2 < 4; mi2++)
            #pragma unroll
            for (int qt = 0; qt < 2; qt++)
                #pragma unroll
                for (int r = 0; r < 4; r++)
                    pub[(mi2 * 8 + qt * 4 + r) * 64 + lane] = oacc[mi2][qt][r];
        if (lq == 0) {
            smf[8192 + w4 * 32 + lm]      = gsum[0];
            smf[8192 + w4 * 32 + 16 + lm] = gsum[1];
        }
    }
    __syncthreads();

    // ---- group 0 combines, normalizes, writes output
    if (grp == 0) {
        float* pub = smf + w4 * 2048;
        #pragma unroll
        for (int mi2 = 0; mi2 < 4; mi2++)
            #pragma unroll
            for (int qt = 0; qt < 2; qt++)
                #pragma unroll
                for (int r = 0; r < 4; r++)
                    oacc[mi2][qt][r] += pub[(mi2 * 8 + qt * 4 + r) * 64 + lane];
        float inv[2];
        inv[0] = 1.f / (gsum[0] + smf[8192 + w4 * 32 + lm]);
        inv[1] = 1.f / (gsum[1] + smf[8192 + w4 * 32 + 16 + lm]);

        // transpose O^T back via smem (region disjoint from publish), coalesced store
        unsigned short* Ow = smem + 17024 + w4 * 2304;  // 32 x 72
        #pragma unroll
        for (int mi2 = 0; mi2 < 4; mi2++)
            #pragma unroll
            for (int qt = 0; qt < 2; qt++) {
                U2S4 t;
                #pragma unroll
                for (int r = 0; r < 4; r++)
                    t.h[r] = f2bf(oacc[mi2][qt][r] * inv[qt]);
                *(uint2*)&Ow[(qt * 16 + lm) * 72 + mi2 * 16 + lq * 4] = t.u;
            }
        __builtin_amdgcn_wave_barrier();  // Ow wave-local
        int b = bh >> 4, h = bh & 15;
        #pragma unroll
        for (int it = 0; it < 4; it++) {
            int q  = it * 8 + (lane >> 3);
            int off = (lane & 7) * 8;
            uint4 val = *(const uint4*)&Ow[q * 72 + off];
            int srw = q0 + w4 * 32 + q;
            *(uint4*)(ob + (size_t)(b * SS + srw) * DD + h * 64 + off) = val;
        }
    }
}

// ---------------------------------------------------------------- Output GEMM
// out[m,e] = sum_d o[m,d] * w_out[e,d] + b_out[e].  M=4096, N=1024, K=1024.
// 128x64 tile -> 512 blocks (2/CU); async dbuf staging, one barrier per BK.
__global__ __launch_bounds__(256) void gemm_out(
    const unsigned short* __restrict__ A,   // o_bf   [4096][1024]
    const unsigned short* __restrict__ Bw,  // wout_bf[1024][1024]
    const float* __restrict__ bias, float* __restrict__ out) {
    const int K = 1024;
    __shared__ unsigned short smem[12288];
    int tid = threadIdx.x;
    int lane = tid & 63, wave = tid >> 6;
    int wm = (wave & 1) * 64, wn = (wave >> 1) * 32;
    int m0 = blockIdx.y * 128, n0 = blockIdx.x * 64;
    int lm = lane & 15, lq = lane >> 4;

    f32x4 acc[4][2] = {};

    int sdst = tid * 8;
    const unsigned short* gA = A  + (size_t)(m0 + (tid >> 2)) * K + (tid & 3) * 8;
    const unsigned short* gB = Bw + (size_t)(n0 + (tid >> 2)) * K + (tid & 3) * 8;

#define OSTAGE(k0, buf) do {                                          \
        async_cp16(gA + (k0),          smem + (buf) + sdst);          \
        async_cp16(gA + 64 * K + (k0), smem + (buf) + 2048 + sdst);   \
        async_cp16(gB + (k0),          smem + (buf) + 4096 + sdst);   \
    } while (0)

    OSTAGE(0, 0);
    for (int k0 = 0; k0 < K; k0 += 64) {
        #pragma unroll
        for (int hf = 0; hf < 2; hf++) {
            int base = hf ? 6144 : 0;
            int obuf = hf ? 0 : 6144;
            __syncthreads();
            int kn = k0 + 32 + hf * 32;
            if (kn < K) OSTAGE(kn, obuf);
            const unsigned short* As = smem + base;
            const unsigned short* Bs = smem + base + 4096;
            U4S8 af[4], bfx[2];
            #pragma unroll
            for (int i = 0; i < 4; i++)
                af[i].u = *(const uint4*)(As + (wm + i * 16 + lm) * 32 + lq * 8);
            #pragma unroll
            for (int i = 0; i < 2; i++)
                bfx[i].u = *(const uint4*)(Bs + (wn + i * 16 + lm) * 32 + lq * 8);
            #pragma unroll
            for (int mi = 0; mi < 4; mi++)
                #pragma unroll
                for (int ni = 0; ni < 2; ni++)
                    acc[mi][ni] = __builtin_amdgcn_mfma_f32_16x16x32_bf16(
                        af[mi].s, bfx[ni].s, acc[mi][ni], 0, 0, 0);
        }
    }
#undef OSTAGE

    #pragma unroll
    for (int mi = 0; mi < 4; mi++) {
        int gr = m0 + wm + mi * 16 + lq * 4;
        #pragma unroll
        for (int ni = 0; ni < 2; ni++) {
            int gc = n0 + wn + ni * 16 + lm;
            float bv = bias[gc];
            #pragma unroll
            for (int r = 0; r < 4; r++)
                out[(size_t)(gr + r) * DD + gc] = acc[mi][ni][r] + bv;
        }
    }
}

// ---------------------------------------------------------------- launch
extern "C" void kernel_launch(void* const* d_in, const int* in_sizes, int n_in,
                              void* d_out, int out_size, void* d_ws, size_t ws_size,
                              hipStream_t stream) {
    const float* x     = (const float*)d_in[0];
    const float* w_qkv = (const float*)d_in[1];
    const float* w_out = (const float*)d_in[2];
    const float* b_out = (const float*)d_in[3];
    float* out = (float*)d_out;

    unsigned short* ws = (unsigned short*)d_ws;
    const size_t NX = (size_t)BB * SS * DD;        // 4,194,304
    unsigned short* x_bf    = ws;
    unsigned short* wqkv_bf = x_bf + NX;
    unsigned short* wout_bf = wqkv_bf + 3145728;
    unsigned short* q_buf   = wout_bf + 1048576;
    unsigned short* k_buf   = q_buf + NX;
    unsigned short* v_buf   = k_buf + NX;
    unsigned short* o_buf   = v_buf + NX;

    cvt_all<<<4096, 256, 0, stream>>>(x, w_qkv, w_out, x_bf, wqkv_bf, wout_bf);
    gemm_qkv<<<dim3(24, 32), 256, 0, stream>>>(x_bf, wqkv_bf, q_buf, k_buf, v_buf);
    attn<<<dim3(16, 32), 512, 0, stream>>>(q_buf, k_buf, v_buf, o_buf);
    gemm_out<<<dim3(16, 32), 256, 0, stream>>>(o_buf, wout_bf, b_out, out);
}

// Round 16
// 191.913 us; speedup vs baseline: 1.1276x; 1.0148x over previous
//
#include <hip/hip_runtime.h>
#include <cstdint>
#include <cstddef>

// Problem constants
#define BB 2
#define SS 2048
#define DD 1024
#define HH 16
#define HDIM 64
// Attention scale 1/sqrt(64)=0.125 and the exp->exp2 fold log2(e) are
// pre-multiplied into q at the gemm_qkv epilogue: 0.125*1.4426950 = 0.18033688.

typedef short bf16x8 __attribute__((ext_vector_type(8)));
typedef short bf16x4 __attribute__((ext_vector_type(4)));
typedef float f32x4 __attribute__((ext_vector_type(4)));
typedef float f32x2 __attribute__((ext_vector_type(2)));

union U4S8 { uint4 u; bf16x8 s; };
union U2S4 { uint2 u; bf16x4 s; unsigned short h[4]; };

#if defined(__HIP_DEVICE_COMPILE__)
# if __has_builtin(__builtin_amdgcn_exp2f)
#  define EXP2(x) __builtin_amdgcn_exp2f(x)   // bare v_exp_f32, no libm envelope
# else
#  define EXP2(x) exp2f(x)
# endif
#else
# define EXP2(x) exp2f(x)
#endif

__device__ __forceinline__ unsigned short f2bf(float f) {
    union { float f; unsigned int u; } c; c.f = f;
    unsigned int u = c.u;
    unsigned int r = (u + 0x7FFFu + ((u >> 16) & 1u)) >> 16;  // RTNE
    return (unsigned short)r;
}

// async global->LDS, 16B per lane. LDS dest must be wave-uniform base + lane*16.
__device__ __forceinline__ void async_cp16(const void* g, void* l) {
    __builtin_amdgcn_global_load_lds(
        (const __attribute__((address_space(1))) void*)g,
        (__attribute__((address_space(3))) void*)l, 16, 0, 0);
}

// ---------------------------------------------------------------- fp32 -> bf16
// One kernel for all three inputs (x:524288, w_qkv:393216, w_out:131072 uint4s).
__global__ __launch_bounds__(256) void cvt_all(
    const float* __restrict__ x, const float* __restrict__ wq,
    const float* __restrict__ wo,
    unsigned short* __restrict__ xb, unsigned short* __restrict__ wqb,
    unsigned short* __restrict__ wob) {
    int i = blockIdx.x * 256 + threadIdx.x;
    const float* in; unsigned short* out; int j;
    if (i < 524288)       { in = x;  out = xb;  j = i; }
    else if (i < 917504)  { in = wq; out = wqb; j = i - 524288; }
    else                  { in = wo; out = wob; j = i - 917504; }
    float4 a = ((const float4*)in)[2 * j];
    float4 b = ((const float4*)in)[2 * j + 1];
    union { uint4 u; unsigned short h[8]; } o;
    o.h[0] = f2bf(a.x); o.h[1] = f2bf(a.y); o.h[2] = f2bf(a.z); o.h[3] = f2bf(a.w);
    o.h[4] = f2bf(b.x); o.h[5] = f2bf(b.y); o.h[6] = f2bf(b.z); o.h[7] = f2bf(b.w);
    ((uint4*)out)[j] = o.u;
}

// ---------------------------------------------------------------- QKV GEMM
// C[m,e] = sum_d x[m,d] * w_qkv[e,d]  (NT). M=4096, N=3072, K=1024.
// 128x128 tile, BK=32, async dbuf staging (one barrier/BK). r16: XOR-swizzled
// LDS — physical chunk tid&3 sources logical chunk (tid&3)^((tid>>3)&3);
// fragment reads at sw=(lq^((lm>>1)&3))*8 -> 2-way banks (free), was 8-way.
__global__ __launch_bounds__(256) void gemm_qkv(
    const unsigned short* __restrict__ A,   // x_bf   [4096][1024]
    const unsigned short* __restrict__ Bw,  // wqkv_bf[3072][1024]
    unsigned short* __restrict__ qb, unsigned short* __restrict__ kb,
    unsigned short* __restrict__ vb) {
    const int K = 1024;
    __shared__ unsigned short smem[18432];
    int tid = threadIdx.x;
    int lane = tid & 63, wave = tid >> 6;
    int wm = (wave & 1) * 64, wn = (wave >> 1) * 64;
    int m0 = blockIdx.y * 128, n0 = blockIdx.x * 128;
    int lm = lane & 15, lq = lane >> 4;

    f32x4 acc[4][4] = {};

    int sdst = tid * 8;  // shorts; lane-contiguous dest
    int lch = (tid & 3) ^ ((tid >> 3) & 3);  // swizzled source chunk
    const unsigned short* gA = A  + (size_t)(m0 + (tid >> 2)) * K + lch * 8;
    const unsigned short* gB = Bw + (size_t)(n0 + (tid >> 2)) * K + lch * 8;
    int sw = (lq ^ ((lm >> 1) & 3)) * 8;     // swizzled read chunk offset

#define GSTAGE(k0, buf) do {                                          \
        async_cp16(gA + (k0),          smem + (buf) + sdst);          \
        async_cp16(gA + 64 * K + (k0), smem + (buf) + 2048 + sdst);   \
        async_cp16(gB + (k0),          smem + (buf) + 4096 + sdst);   \
        async_cp16(gB + 64 * K + (k0), smem + (buf) + 6144 + sdst);   \
    } while (0)

    GSTAGE(0, 0);
    for (int k0 = 0; k0 < K; k0 += 64) {
        #pragma unroll
        for (int hf = 0; hf < 2; hf++) {
            int base = hf ? 8192 : 0;
            int obuf = hf ? 0 : 8192;
            __syncthreads();  // drains this buffer's loads; other buffer free
            int kn = k0 + 32 + hf * 32;
            if (kn < K) GSTAGE(kn, obuf);
            const unsigned short* As = smem + base;
            const unsigned short* Bs = smem + base + 4096;
            U4S8 af[4], bfx[4];
            #pragma unroll
            for (int i = 0; i < 4; i++) {
                af[i].u  = *(const uint4*)(As + (wm + i * 16 + lm) * 32 + sw);
                bfx[i].u = *(const uint4*)(Bs + (wn + i * 16 + lm) * 32 + sw);
            }
            #pragma unroll
            for (int mi = 0; mi < 4; mi++)
                #pragma unroll
                for (int ni = 0; ni < 4; ni++)
                    acc[mi][ni] = __builtin_amdgcn_mfma_f32_16x16x32_bf16(
                        af[mi].s, bfx[ni].s, acc[mi][ni], 0, 0, 0);
        }
    }
#undef GSTAGE
    __syncthreads();  // staging LDS done before epilogue alias reuse

    // Epilogue. C/D layout: col=lane&15, row=(lane>>4)*4+reg.
    unsigned short* Lw = smem + wave * 4608;  // 64 x 72
    int b = m0 >> 11;
    int s_base = (m0 + wm) & 2047;
    if (n0 < 1024) {
        // ---- v: transpose (store [B,H,HD,S]): Lw[hd][s], b64 packed writes
        int h = (n0 + wn) >> 6;
        #pragma unroll
        for (int mi = 0; mi < 4; mi++)
            #pragma unroll
            for (int ni = 0; ni < 4; ni++) {
                U2S4 t;
                #pragma unroll
                for (int r = 0; r < 4; r++)
                    t.h[r] = f2bf(acc[mi][ni][r]);
                *(uint2*)&Lw[(ni * 16 + lm) * 72 + mi * 16 + lq * 4] = t.u;
            }
        __builtin_amdgcn_wave_barrier();
        unsigned short* vdst = vb + ((size_t)(b * HH + h) * HDIM) * SS + s_base;
        #pragma unroll
        for (int it = 0; it < 8; it++) {
            int hd = it * 8 + (lane >> 3);
            int so = (lane & 7) * 8;
            uint4 val = *(const uint4*)&Lw[hd * 72 + so];
            *(uint4*)(vdst + (size_t)hd * SS + so) = val;
        }
    } else {
        // ---- q/k: gather (store [B,H,S,HD]): Lw[s][hd], no transpose
        bool isq = n0 < 2048;
        unsigned short* dst = isq ? qb : kb;
        float scale = isq ? 0.18033688f : 1.0f;  // q: fold softmax scale * log2(e)
        int h = ((n0 + wn) >> 6) & 15;
        #pragma unroll
        for (int mi = 0; mi < 4; mi++)
            #pragma unroll
            for (int ni = 0; ni < 4; ni++)
                #pragma unroll
                for (int r = 0; r < 4; r++)
                    Lw[(mi * 16 + lq * 4 + r) * 72 + ni * 16 + lm] =
                        f2bf(acc[mi][ni][r] * scale);
        __builtin_amdgcn_wave_barrier();
        unsigned short* qdst =
            dst + ((size_t)(b * HH + h) * SS + s_base) * HDIM;
        #pragma unroll
        for (int it = 0; it < 8; it++) {
            int srw = it * 8 + (lane >> 3);
            int so = (lane & 7) * 8;
            uint4 val = *(const uint4*)&Lw[srw * 72 + so];
            *(uint4*)(qdst + (size_t)srw * HDIM + so) = val;
        }
    }
}

// ---------------------------------------------------------------- Flash attention
// r15 kernel (unchanged): 512-thr k-split blocks, async dbuf, XOR swizzle,
// K=32 PV via KAPPA-permuted K staging.
__global__ __launch_bounds__(512) void attn(
    const unsigned short* __restrict__ qb,  // [B,H,S,HD] pre-scaled (incl. log2e)
    const unsigned short* __restrict__ kb,  // [B,H,S,HD]
    const unsigned short* __restrict__ vb,  // [B,H,HD,S] (transposed)
    unsigned short* __restrict__ ob) {      // [B,S,D]
    int bh = blockIdx.y;
    int q0 = blockIdx.x * 128;
    int tid = threadIdx.x, lane = tid & 63, wave = tid >> 6;
    int grp = wave >> 2;      // k-half
    int w4  = wave & 3;       // wave-in-group: owns q rows w4*32..+31
    int lm = lane & 15, lq = lane >> 4;

    // [pair 2][KA|KB|VA|VB, 4096 shorts each] = 32768 shorts = 64 KB
    __shared__ unsigned short smem[32768];
    float* smf = (float*)smem;

    const unsigned short* qg = qb + (size_t)bh * SS * HDIM;
    const unsigned short* kg = kb + (size_t)bh * SS * HDIM;
    const unsigned short* vg = vb + (size_t)bh * HDIM * SS;

    // Q fragments (both groups load the same q rows for their k-half)
    U4S8 qf[2][2];
    #pragma unroll
    for (int qt = 0; qt < 2; qt++)
        #pragma unroll
        for (int ks = 0; ks < 2; ks++)
            qf[qt][ks].u = *(const uint4*)(
                qg + (size_t)(q0 + w4 * 32 + qt * 16 + lm) * HDIM + ks * 32 + lq * 8);

    f32x4 oacc[4][2] = {};        // O^T[hd-tile][q-subtile] (this group's k-half)
    f32x2 lsum2[2] = {};

    // ---- loop-invariant swizzled LDS read indices within a 64x64 tile (shorts)
    int lm7 = lm & 7;
    int kidx = lm * 64 + 8 * (lq ^ lm7);          // kf b128 (slot rows)
    int vidx[2];                                  // vf b128: kpos kb*32+lq*8 (true k)
    #pragma unroll
    for (int kblk = 0; kblk < 2; kblk++)
        vidx[kblk] = lm * 64 + 8 * (((kblk << 2) | lq) ^ lm7);

    // ---- staging: 512 threads x 4 async-16B = one 128-wide K-tile (K + V)
    // K source row is KAPPA-permuted: LDS slot s holds k-row kappa(s), where
    // kappa(s) = 32*(s>>5) + 8*((s>>2)&3) + 4*((s>>4)&1) + (s&3)  (s in 0..63)
    int sr  = tid >> 3;                // LDS slot row 0..63
    int s5  = sr & 31;
    int kap = (sr & 32) + (((s5 >> 2) & 3) << 3) + (((s5 >> 4) & 1) << 2) + (s5 & 3);
    int lch = (tid & 7) ^ (sr & 7);    // chunk swizzle keyed by SLOT row
    int sdst = tid * 8;                // shorts within each 4096-short region
    const unsigned short* kpA = kg + (size_t)kap * HDIM + lch * 8;   // slots 0-63
    const unsigned short* kpB = kpA + 64 * HDIM;                     // slots 64-127
    const unsigned short* vpA = vg + (size_t)sr * SS + lch * 8;      // kpos 0-63
    const unsigned short* vpB = vpA + 64;                            // kpos 64-127

    #define STAGE(pbase)                                                       \
        do {                                                                   \
            async_cp16(kpA, smem + (pbase) + sdst);                            \
            async_cp16(kpB, smem + (pbase) + 4096 + sdst);                     \
            async_cp16(vpA, smem + (pbase) + 8192 + sdst);                     \
            async_cp16(vpB, smem + (pbase) + 12288 + sdst);                    \
            kpA += 128 * HDIM; kpB += 128 * HDIM; vpA += 128; vpB += 128;      \
        } while (0)

    STAGE(0);

    for (int kt = 0; kt < SS / 128; kt += 2) {
        #pragma unroll
        for (int hf = 0; hf < 2; hf++) {
            int cbase = hf ? 16384 : 0;      // compute pair
            int obase = hf ? 0 : 16384;      // stage target pair
            __syncthreads();  // drains vmcnt: compute pair's loads landed
            STAGE(obase);  // last iter over-reads one tile into adjacent ws buf

            int kbase = cbase + grp * 4096;
            int vbase = cbase + 8192 + grp * 4096;

            // ---- S^T then P^T = 2^(S^T): tile-pair halves fill the K=32
            //      B-operand directly (kappa staging makes r-index == j)
            U4S8 pb8[2][2];   // [kblk][qt]: full 16x16x32 B-operand fragments
            #pragma unroll
            for (int mi = 0; mi < 4; mi++) {
                U4S8 kf0, kf1;
                kf0.u = *(const uint4*)(smem + kbase + mi * 1024 + kidx);
                kf1.u = *(const uint4*)(smem + kbase + mi * 1024 + (kidx ^ 32));
                #pragma unroll
                for (int qt = 0; qt < 2; qt++) {
                    f32x4 sa = {};
                    sa = __builtin_amdgcn_mfma_f32_16x16x32_bf16(kf0.s, qf[qt][0].s, sa, 0, 0, 0);
                    sa = __builtin_amdgcn_mfma_f32_16x16x32_bf16(kf1.s, qf[qt][1].s, sa, 0, 0, 0);
                    float p0 = EXP2(sa[0]);
                    float p1 = EXP2(sa[1]);
                    float p2 = EXP2(sa[2]);
                    float p3 = EXP2(sa[3]);
                    f32x2 a01; a01[0] = p0; a01[1] = p1;
                    f32x2 a23; a23[0] = p2; a23[1] = p3;
                    lsum2[qt] += a01;
                    lsum2[qt] += a23;
                    unsigned int b0 = __float_as_uint(p0) + 0x8000u;  // ties-away
                    unsigned int b1 = __float_as_uint(p1) + 0x8000u;
                    unsigned int b2 = __float_as_uint(p2) + 0x8000u;
                    unsigned int b3 = __float_as_uint(p3) + 0x8000u;
                    unsigned int lo = __builtin_amdgcn_perm(b1, b0, 0x07060302u);
                    unsigned int hi = __builtin_amdgcn_perm(b3, b2, 0x07060302u);
                    if ((mi & 1) == 0) { pb8[mi >> 1][qt].u.x = lo; pb8[mi >> 1][qt].u.y = hi; }
                    else               { pb8[mi >> 1][qt].u.z = lo; pb8[mi >> 1][qt].u.w = hi; }
                }
            }

            // ---- O^T += V^T·P^T at K=32
            #pragma unroll
            for (int mi2 = 0; mi2 < 4; mi2++) {
                #pragma unroll
                for (int kblk = 0; kblk < 2; kblk++) {
                    U4S8 vf;
                    vf.u = *(const uint4*)(smem + vbase + mi2 * 1024 + vidx[kblk]);
                    oacc[mi2][0] = __builtin_amdgcn_mfma_f32_16x16x32_bf16(
                        vf.s, pb8[kblk][0].s, oacc[mi2][0], 0, 0, 0);
                    oacc[mi2][1] = __builtin_amdgcn_mfma_f32_16x16x32_bf16(
                        vf.s, pb8[kblk][1].s, oacc[mi2][1], 0, 0, 0);
                }
            }
        }
    }
    #undef STAGE

    // ---- per-group row sums (lanes lm,+16,+32,+48 hold disjoint k partials)
    float gsum[2];
    #pragma unroll
    for (int qt = 0; qt < 2; qt++) {
        float s = lsum2[qt][0] + lsum2[qt][1];
        s += __shfl_xor(s, 16);
        s += __shfl_xor(s, 32);
        gsum[qt] = s;
    }

    __syncthreads();  // all compute done; drains stray over-read loads

    // ---- group 1 publishes raw O^T + sums (SoA: word j at j*64+lane, no conflicts)
    if (grp == 1) {
        float* pub = smf + w4 * 2048;
        #pragma unroll
        for (int mi2 = 0; mi2 < 4; mi2++)
            #pragma unroll
            for (int qt = 0; qt < 2; qt++)
                #pragma unroll
                for (int r = 0; r < 4; r++)
                    pub[(mi2 * 8 + qt * 4 + r) * 64 + lane] = oacc[mi2][qt][r];
        if (lq == 0) {
            smf[8192 + w4 * 32 + lm]      = gsum[0];
            smf[8192 + w4 * 32 + 16 + lm] = gsum[1];
        }
    }
    __syncthreads();

    // ---- group 0 combines, normalizes, writes output
    if (grp == 0) {
        float* pub = smf + w4 * 2048;
        #pragma unroll
        for (int mi2 = 0; mi2 < 4; mi2++)
            #pragma unroll
            for (int qt = 0; qt < 2; qt++)
                #pragma unroll
                for (int r = 0; r < 4; r++)
                    oacc[mi2][qt][r] += pub[(mi2 * 8 + qt * 4 + r) * 64 + lane];
        float inv[2];
        inv[0] = 1.f / (gsum[0] + smf[8192 + w4 * 32 + lm]);
        inv[1] = 1.f / (gsum[1] + smf[8192 + w4 * 32 + 16 + lm]);

        // transpose O^T back via smem (region disjoint from publish), coalesced store
        unsigned short* Ow = smem + 17024 + w4 * 2304;  // 32 x 72
        #pragma unroll
        for (int mi2 = 0; mi2 < 4; mi2++)
            #pragma unroll
            for (int qt = 0; qt < 2; qt++) {
                U2S4 t;
                #pragma unroll
                for (int r = 0; r < 4; r++)
                    t.h[r] = f2bf(oacc[mi2][qt][r] * inv[qt]);
                *(uint2*)&Ow[(qt * 16 + lm) * 72 + mi2 * 16 + lq * 4] = t.u;
            }
        __builtin_amdgcn_wave_barrier();  // Ow wave-local
        int b = bh >> 4, h = bh & 15;
        #pragma unroll
        for (int it = 0; it < 4; it++) {
            int q  = it * 8 + (lane >> 3);
            int off = (lane & 7) * 8;
            uint4 val = *(const uint4*)&Ow[q * 72 + off];
            int srw = q0 + w4 * 32 + q;
            *(uint4*)(ob + (size_t)(b * SS + srw) * DD + h * 64 + off) = val;
        }
    }
}

// ---------------------------------------------------------------- Output GEMM
// out[m,e] = sum_d o[m,d] * w_out[e,d] + b_out[e].  M=4096, N=1024, K=1024.
// 128x64 tile -> 512 blocks (2/CU). r16: BK=64 per barrier (16 barriers,
// 16 MFMA/wave/barrier — was 32 barriers x 8) + XOR-swizzled LDS.
// Buffer layout (shorts): As_k0[0,4096) As_k1[4096,8192) Bs_k0[8192,10240)
// Bs_k1[10240,12288); dbuf at +12288. Total 24576 shorts = 48 KB.
__global__ __launch_bounds__(256) void gemm_out(
    const unsigned short* __restrict__ A,   // o_bf   [4096][1024]
    const unsigned short* __restrict__ Bw,  // wout_bf[1024][1024]
    const float* __restrict__ bias, float* __restrict__ out) {
    const int K = 1024;
    __shared__ unsigned short smem[24576];
    int tid = threadIdx.x;
    int lane = tid & 63, wave = tid >> 6;
    int wm = (wave & 1) * 64, wn = (wave >> 1) * 32;
    int m0 = blockIdx.y * 128, n0 = blockIdx.x * 64;
    int lm = lane & 15, lq = lane >> 4;

    f32x4 acc[4][2] = {};

    int sdst = tid * 8;
    int lch = (tid & 3) ^ ((tid >> 3) & 3);  // swizzled source chunk
    const unsigned short* gA = A  + (size_t)(m0 + (tid >> 2)) * K + lch * 8;
    const unsigned short* gB = Bw + (size_t)(n0 + (tid >> 2)) * K + lch * 8;
    int sw = (lq ^ ((lm >> 1) & 3)) * 8;     // swizzled read chunk offset

#define OSTAGE(k0, buf) do {                                               \
        async_cp16(gA + (k0),               smem + (buf) + sdst);          \
        async_cp16(gA + 64 * K + (k0),      smem + (buf) + 2048 + sdst);   \
        async_cp16(gA + (k0) + 32,          smem + (buf) + 4096 + sdst);   \
        async_cp16(gA + 64 * K + (k0) + 32, smem + (buf) + 6144 + sdst);   \
        async_cp16(gB + (k0),               smem + (buf) + 8192 + sdst);   \
        async_cp16(gB + (k0) + 32,          smem + (buf) + 10240 + sdst);  \
    } while (0)

    OSTAGE(0, 0);
    for (int k0 = 0; k0 < K; k0 += 128) {
        #pragma unroll
        for (int hf = 0; hf < 2; hf++) {
            int base = hf ? 12288 : 0;
            int obuf = hf ? 0 : 12288;
            __syncthreads();
            int kn = k0 + 64 + hf * 64;
            if (kn < K) OSTAGE(kn, obuf);
            #pragma unroll
            for (int kc = 0; kc < 2; kc++) {
                const unsigned short* As = smem + base + kc * 4096;
                const unsigned short* Bs = smem + base + 8192 + kc * 2048;
                U4S8 af[4], bfx[2];
                #pragma unroll
                for (int i = 0; i < 4; i++)
                    af[i].u = *(const uint4*)(As + (wm + i * 16 + lm) * 32 + sw);
                #pragma unroll
                for (int i = 0; i < 2; i++)
                    bfx[i].u = *(const uint4*)(Bs + (wn + i * 16 + lm) * 32 + sw);
                #pragma unroll
                for (int mi = 0; mi < 4; mi++)
                    #pragma unroll
                    for (int ni = 0; ni < 2; ni++)
                        acc[mi][ni] = __builtin_amdgcn_mfma_f32_16x16x32_bf16(
                            af[mi].s, bfx[ni].s, acc[mi][ni], 0, 0, 0);
            }
        }
    }
#undef OSTAGE

    #pragma unroll
    for (int mi = 0; mi < 4; mi++) {
        int gr = m0 + wm + mi * 16 + lq * 4;
        #pragma unroll
        for (int ni = 0; ni < 2; ni++) {
            int gc = n0 + wn + ni * 16 + lm;
            float bv = bias[gc];
            #pragma unroll
            for (int r = 0; r < 4; r++)
                out[(size_t)(gr + r) * DD + gc] = acc[mi][ni][r] + bv;
        }
    }
}

// ---------------------------------------------------------------- launch
extern "C" void kernel_launch(void* const* d_in, const int* in_sizes, int n_in,
                              void* d_out, int out_size, void* d_ws, size_t ws_size,
                              hipStream_t stream) {
    const float* x     = (const float*)d_in[0];
    const float* w_qkv = (const float*)d_in[1];
    const float* w_out = (const float*)d_in[2];
    const float* b_out = (const float*)d_in[3];
    float* out = (float*)d_out;

    unsigned short* ws = (unsigned short*)d_ws;
    const size_t NX = (size_t)BB * SS * DD;        // 4,194,304
    unsigned short* x_bf    = ws;
    unsigned short* wqkv_bf = x_bf + NX;
    unsigned short* wout_bf = wqkv_bf + 3145728;
    unsigned short* q_buf   = wout_bf + 1048576;
    unsigned short* k_buf   = q_buf + NX;
    unsigned short* v_buf   = k_buf + NX;
    unsigned short* o_buf   = v_buf + NX;

    cvt_all<<<4096, 256, 0, stream>>>(x, w_qkv, w_out, x_bf, wqkv_bf, wout_bf);
    gemm_qkv<<<dim3(24, 32), 256, 0, stream>>>(x_bf, wqkv_bf, q_buf, k_buf, v_buf);
    attn<<<dim3(16, 32), 512, 0, stream>>>(q_buf, k_buf, v_buf, o_buf);
    gemm_out<<<dim3(16, 32), 256, 0, stream>>>(o_buf, wout_bf, b_out, out);
}